// Round 3
// baseline (1771.463 us; speedup 1.0000x reference)
//
#include <hip/hip_runtime.h>
#include <math.h>

// GCN_481036337415: 4-layer GCNConv (PyG norm w/ self-loops) + linear head.
// N=500000 nodes, E=16000000 edges. dims: 8 ->4 ->4 ->2 ->2 ->112.
//
// R1: device f32 atomics ~20 G/s -> atomic scatter = 10.5 ms.
// R2: padded bucket-CSR, 16M return-atomics + scattered 4B stores = 2.0 ms.
// R3: two-pass WG binning into 977 dst buckets + per-bucket LDS gathers
//     = 1.62 ms; gathers 343 us @ 29% occupancy.
// R4: SEG=4 segmentation -> occupancy 72% but gathers STILL 343 us,
//     FETCH still 542 MB: random hin[src] misses L2 (8MB vs 4MB/XCD,
//     chip-wide random) -> fabric random-transaction wall (~47 G/s).
// R5 (this): make gathers L2-LOCAL. k_rebin counting-sorts each bucket's
//     entries by src region (src>>14: 32 regions, 256KB hin slice each).
//     All gather WGs walk spans front-to-back together -> chip-wide
//     working set ~1-2 regions -> hin loads hit L2. Region runs padded
//     to uint4 alignment with sentinel words (bit31 set, skipped).
//     SEG 4->2 (occupancy proven not the limiter).

constexpr int NN = 500000;
constexpr int NE = 16000000;

constexpr int BSH  = 9;                        // 512 nodes per bucket
constexpr int BNODES = 1 << BSH;               // 512
constexpr int NBK  = (NN + BNODES - 1) / BNODES;  // 977 buckets
constexpr int BCAP = 18432;                    // entries/bucket (mean 16376, +16 sigma)
constexpr int ECHUNK = 16384;                  // edges per binning WG
constexpr int NBA = (NE + ECHUNK - 1) / ECHUNK;   // 977 WGs
constexpr int SEG = 2;                         // segments per bucket (gather)
constexpr int NSR = 32;                        // src regions (src >> RSH)
constexpr int RSH = 14;                        // 16384 nodes / region

__device__ __forceinline__ void aadd(float* p, float v) {
    unsafeAtomicAdd(p, v);
}

// ======================= bucket-binned path =======================

__global__ __launch_bounds__(256) void k_tinit(int* __restrict__ tail) {
    int i = blockIdx.x * 256 + threadIdx.x;
    if (i < NBK) tail[i] = i * BCAP;
}

// Stage 1: two-pass WG binning by dst bucket. Pass1: LDS bucket histogram.
// Reserve: one global atomicAdd per (WG,bucket). Pass2: LDS re-rank +
// packed write (local_dst<<19 | src), runs of ~17 entries -> line-efficient.
__global__ __launch_bounds__(256) void k_binA(const int* __restrict__ src,
                                              const int* __restrict__ dst,
                                              int* __restrict__ tail,
                                              unsigned* __restrict__ bins) {
    __shared__ int cnt[NBK];
    __shared__ int bbase[NBK];
    const int t = threadIdx.x;
    for (int k = t; k < NBK; k += 256) cnt[k] = 0;
    __syncthreads();

    const long e0 = (long)blockIdx.x * ECHUNK;
    const int ne = (int)min((long)ECHUNK, (long)NE - e0);
    const int g0 = (int)(e0 >> 2);
    const int ng = ne >> 2;  // chunk%4==0 -> exact

    for (int g = t; g < ng; g += 256) {
        int4 d = ((const int4*)dst)[g0 + g];
        atomicAdd(&cnt[d.x >> BSH], 1);
        atomicAdd(&cnt[d.y >> BSH], 1);
        atomicAdd(&cnt[d.z >> BSH], 1);
        atomicAdd(&cnt[d.w >> BSH], 1);
    }
    __syncthreads();
    for (int k = t; k < NBK; k += 256) {
        int c = cnt[k];
        bbase[k] = c ? atomicAdd(&tail[k], c) : 0;
        cnt[k] = 0;
    }
    __syncthreads();
    for (int g = t; g < ng; g += 256) {
        int4 d = ((const int4*)dst)[g0 + g];
        int4 s = ((const int4*)src)[g0 + g];
        int b, r, idx;
        b = d.x >> BSH; r = atomicAdd(&cnt[b], 1); idx = bbase[b] + r;
        if (idx < (b + 1) * BCAP)
            bins[idx] = ((unsigned)(d.x & (BNODES - 1)) << 19) | (unsigned)s.x;
        b = d.y >> BSH; r = atomicAdd(&cnt[b], 1); idx = bbase[b] + r;
        if (idx < (b + 1) * BCAP)
            bins[idx] = ((unsigned)(d.y & (BNODES - 1)) << 19) | (unsigned)s.y;
        b = d.z >> BSH; r = atomicAdd(&cnt[b], 1); idx = bbase[b] + r;
        if (idx < (b + 1) * BCAP)
            bins[idx] = ((unsigned)(d.z & (BNODES - 1)) << 19) | (unsigned)s.z;
        b = d.w >> BSH; r = atomicAdd(&cnt[b], 1); idx = bbase[b] + r;
        if (idx < (b + 1) * BCAP)
            bins[idx] = ((unsigned)(d.w & (BNODES - 1)) << 19) | (unsigned)s.w;
    }
}

// Stage 2: per-bucket counting sort by src region. Region runs are packed
// from the bucket base, each run start 4-aligned; gaps filled with sentinel
// 0x80000000. regoff[b][0..NSR] = aligned run starts (+ total span).
__global__ __launch_bounds__(256) void k_rebin(const unsigned* __restrict__ bins0,
                                               const int* __restrict__ tail,
                                               unsigned* __restrict__ bins1,
                                               int* __restrict__ regoff) {
    __shared__ int c1[4][NSR];    // pass1 per-wave counts
    __shared__ int c2[4][NSR];    // pass2 per-wave ranks
    __shared__ int wb[4][NSR];    // per-wave write bases
    __shared__ int off[NSR + 1];  // aligned run starts
    __shared__ int rtot[NSR];     // payload counts
    const int b = blockIdx.x;
    const int t = threadIdx.x;
    const int w = t >> 6;
    if (t < 4 * NSR) { ((int*)c1)[t] = 0; ((int*)c2)[t] = 0; }
    __syncthreads();
    const int base = b * BCAP;
    const int n = min(tail[b] - base, BCAP);
    const unsigned* e0 = bins0 + base;
    for (int j = t; j < n; j += 256)
        atomicAdd(&c1[w][(e0[j] & 0x7FFFFu) >> RSH], 1);
    __syncthreads();
    if (t == 0) {
        int o = 0;
        for (int r = 0; r < NSR; ++r) {
            off[r] = o;
            int acc = o;
            wb[0][r] = acc; acc += c1[0][r];
            wb[1][r] = acc; acc += c1[1][r];
            wb[2][r] = acc; acc += c1[2][r];
            wb[3][r] = acc; acc += c1[3][r];
            rtot[r] = acc - o;
            o = (acc - o + o + 3) & ~3;  // align4(o + tot)
        }
        off[NSR] = o;
    }
    __syncthreads();
    // sentinel pads between runs
    if (t < NSR) {
        for (int j = off[t] + rtot[t]; j < off[t + 1]; ++j)
            if (j < BCAP) bins1[base + j] = 0x80000000u;
    }
    if (t <= NSR) regoff[b * (NSR + 1) + t] = off[t];
    // pass 2: scatter into region runs (L2-local: within 72KB bucket window)
    for (int j = t; j < n; j += 256) {
        unsigned v = e0[j];
        int r = (v & 0x7FFFFu) >> RSH;
        int k = atomicAdd(&c2[w][r], 1);
        int idx = wb[w][r] + k;
        if (idx < BCAP) bins1[base + idx] = v;
    }
}

// Segmented per-bucket degree count over the region-sorted span.
__global__ __launch_bounds__(256) void g_degp(const unsigned* __restrict__ bins,
                                              const int* __restrict__ regoff,
                                              int* __restrict__ parti) {
    __shared__ int cnt[BNODES];
    const int b = blockIdx.x / SEG;
    const int s = blockIdx.x % SEG;
    const int t = threadIdx.x;
    cnt[t] = 0;
    cnt[t + 256] = 0;
    __syncthreads();
    int span = regoff[b * (NSR + 1) + NSR];
    if (span > BCAP) span = BCAP & ~3;
    const unsigned* e = bins + (size_t)b * BCAP;
    const int ng = span >> 2;
    const int ga = (s * ng) / SEG, gb = ((s + 1) * ng) / SEG;
    for (int g = ga + t; g < gb; g += 256) {
        uint4 v = ((const uint4*)e)[g];
        if ((int)v.x >= 0) atomicAdd(&cnt[v.x >> 19], 1);
        if ((int)v.y >= 0) atomicAdd(&cnt[v.y >> 19], 1);
        if ((int)v.z >= 0) atomicAdd(&cnt[v.z >> 19], 1);
        if ((int)v.w >= 0) atomicAdd(&cnt[v.w >> 19], 1);
    }
    __syncthreads();
    int* p = parti + ((size_t)(b * SEG + s) << BSH);
    p[t] = cnt[t];
    p[t + 256] = cnt[t + 256];
}

__global__ __launch_bounds__(256) void k_dinvp(const int* __restrict__ parti,
                                               float* __restrict__ dinv) {
    int i = blockIdx.x * 256 + threadIdx.x;
    if (i >= NN) return;
    const int b = i >> BSH, r = i & (BNODES - 1);
    int c = 0;
#pragma unroll
    for (int s = 0; s < SEG; ++s) c += parti[((size_t)(b * SEG + s) << BSH) + r];
    dinv[i] = rsqrtf((float)c + 1.0f);  // +1 self-loop
}

// T1: hp = dinv * (x @ W1.T)
__global__ __launch_bounds__(256) void k_t1n(const float* __restrict__ x,
                                             const float* __restrict__ W,
                                             const float* __restrict__ dinv,
                                             float* __restrict__ hp) {
    int i = blockIdx.x * 256 + threadIdx.x;
    if (i >= NN) return;
    float4 x0 = ((const float4*)x)[2 * i];
    float4 x1 = ((const float4*)x)[2 * i + 1];
    float xi[8] = {x0.x, x0.y, x0.z, x0.w, x1.x, x1.y, x1.z, x1.w};
    float di = dinv[i];
    float o[4];
#pragma unroll
    for (int j = 0; j < 4; ++j) {
        float s = 0.f;
#pragma unroll
        for (int k = 0; k < 8; ++k) s = fmaf(xi[k], W[j * 8 + k], s);
        o[j] = di * s;
    }
    ((float4*)hp)[i] = make_float4(o[0], o[1], o[2], o[3]);
}

// Segmented per-bucket gather over the region-sorted span: LDS accumulate
// hp[src] (L2-local by region order), write coalesced partial tile.
template <int IND>
__global__ __launch_bounds__(256) void g_part(const unsigned* __restrict__ bins,
                                              const int* __restrict__ regoff,
                                              const float* __restrict__ hin,
                                              float* __restrict__ part) {
    constexpr int STR = (IND == 4) ? 5 : 3;  // pad stride vs 32 banks
    __shared__ float acc[BNODES * STR];
    const int b = blockIdx.x / SEG;
    const int s = blockIdx.x % SEG;
    const int t = threadIdx.x;
    for (int k = t; k < BNODES * STR; k += 256) acc[k] = 0.f;
    __syncthreads();
    int span = regoff[b * (NSR + 1) + NSR];
    if (span > BCAP) span = BCAP & ~3;
    const unsigned* e = bins + (size_t)b * BCAP;
    const int ng = span >> 2;
    const int ga = (s * ng) / SEG, gb = ((s + 1) * ng) / SEG;
    for (int g = ga + t; g < gb; g += 256) {
        uint4 v = ((const uint4*)e)[g];
        if constexpr (IND == 4) {
            if ((int)v.x >= 0) {
                float4 h = ((const float4*)hin)[v.x & 0x7FFFFu];
                const unsigned l = v.x >> 19;
                atomicAdd(&acc[l * 5 + 0], h.x); atomicAdd(&acc[l * 5 + 1], h.y);
                atomicAdd(&acc[l * 5 + 2], h.z); atomicAdd(&acc[l * 5 + 3], h.w);
            }
            if ((int)v.y >= 0) {
                float4 h = ((const float4*)hin)[v.y & 0x7FFFFu];
                const unsigned l = v.y >> 19;
                atomicAdd(&acc[l * 5 + 0], h.x); atomicAdd(&acc[l * 5 + 1], h.y);
                atomicAdd(&acc[l * 5 + 2], h.z); atomicAdd(&acc[l * 5 + 3], h.w);
            }
            if ((int)v.z >= 0) {
                float4 h = ((const float4*)hin)[v.z & 0x7FFFFu];
                const unsigned l = v.z >> 19;
                atomicAdd(&acc[l * 5 + 0], h.x); atomicAdd(&acc[l * 5 + 1], h.y);
                atomicAdd(&acc[l * 5 + 2], h.z); atomicAdd(&acc[l * 5 + 3], h.w);
            }
            if ((int)v.w >= 0) {
                float4 h = ((const float4*)hin)[v.w & 0x7FFFFu];
                const unsigned l = v.w >> 19;
                atomicAdd(&acc[l * 5 + 0], h.x); atomicAdd(&acc[l * 5 + 1], h.y);
                atomicAdd(&acc[l * 5 + 2], h.z); atomicAdd(&acc[l * 5 + 3], h.w);
            }
        } else {
            if ((int)v.x >= 0) {
                float2 h = ((const float2*)hin)[v.x & 0x7FFFFu];
                const unsigned l = v.x >> 19;
                atomicAdd(&acc[l * 3 + 0], h.x); atomicAdd(&acc[l * 3 + 1], h.y);
            }
            if ((int)v.y >= 0) {
                float2 h = ((const float2*)hin)[v.y & 0x7FFFFu];
                const unsigned l = v.y >> 19;
                atomicAdd(&acc[l * 3 + 0], h.x); atomicAdd(&acc[l * 3 + 1], h.y);
            }
            if ((int)v.z >= 0) {
                float2 h = ((const float2*)hin)[v.z & 0x7FFFFu];
                const unsigned l = v.z >> 19;
                atomicAdd(&acc[l * 3 + 0], h.x); atomicAdd(&acc[l * 3 + 1], h.y);
            }
            if ((int)v.w >= 0) {
                float2 h = ((const float2*)hin)[v.w & 0x7FFFFu];
                const unsigned l = v.w >> 19;
                atomicAdd(&acc[l * 3 + 0], h.x); atomicAdd(&acc[l * 3 + 1], h.y);
            }
        }
    }
    __syncthreads();
    const size_t pb = (size_t)(b * SEG + s) << BSH;
    if constexpr (IND == 4) {
        for (int r = t; r < BNODES; r += 256)
            ((float4*)part)[pb + r] = make_float4(acc[r * 5 + 0], acc[r * 5 + 1],
                                                  acc[r * 5 + 2], acc[r * 5 + 3]);
    } else {
        for (int r = t; r < BNODES; r += 256)
            ((float2*)part)[pb + r] = make_float2(acc[r * 3 + 0], acc[r * 3 + 1]);
    }
}

// Per-node finish: sum SEG partials + self, *dinv +bias, activation,
// next-W transform, dinv prescale, coalesced write.
template <int IND, int OUTD, bool RELU>
__global__ __launch_bounds__(256) void k_finp(const float* __restrict__ part,
                                              const float* __restrict__ dinv,
                                              const float* __restrict__ hin,
                                              const float* __restrict__ bias,
                                              const float* __restrict__ Wn,
                                              float* __restrict__ hout) {
    int i = blockIdx.x * 256 + threadIdx.x;
    if (i >= NN) return;
    const int b = i >> BSH, r = i & (BNODES - 1);
    const float di = dinv[i];
    float h[IND];
    if constexpr (IND == 4) {
        float4 sv = ((const float4*)hin)[i];
        float a0 = sv.x, a1 = sv.y, a2 = sv.z, a3 = sv.w;
#pragma unroll
        for (int s = 0; s < SEG; ++s) {
            float4 p = ((const float4*)part)[((size_t)(b * SEG + s) << BSH) + r];
            a0 += p.x; a1 += p.y; a2 += p.z; a3 += p.w;
        }
        h[0] = di * a0 + bias[0];
        h[1] = di * a1 + bias[1];
        h[2] = di * a2 + bias[2];
        h[3] = di * a3 + bias[3];
    } else {
        float2 sv = ((const float2*)hin)[i];
        float a0 = sv.x, a1 = sv.y;
#pragma unroll
        for (int s = 0; s < SEG; ++s) {
            float2 p = ((const float2*)part)[((size_t)(b * SEG + s) << BSH) + r];
            a0 += p.x; a1 += p.y;
        }
        h[0] = di * a0 + bias[0];
        h[1] = di * a1 + bias[1];
    }
#pragma unroll
    for (int k = 0; k < IND; ++k) h[k] = RELU ? fmaxf(h[k], 0.f) : tanhf(h[k]);
    float o[OUTD];
#pragma unroll
    for (int q = 0; q < OUTD; ++q) {
        float s = 0.f;
#pragma unroll
        for (int k = 0; k < IND; ++k) s = fmaf(h[k], Wn[q * IND + k], s);
        o[q] = di * s;
    }
    if constexpr (OUTD == 4)
        ((float4*)hout)[i] = make_float4(o[0], o[1], o[2], o[3]);
    else
        ((float2*)hout)[i] = make_float2(o[0], o[1]);
}

// Final finish: conv4 tanh -> h[N,2] straight into out chunk.
__global__ __launch_bounds__(256) void k_flast(const float* __restrict__ part,
                                               const float* __restrict__ dinv,
                                               const float* __restrict__ hin,
                                               const float* __restrict__ b4,
                                               float* __restrict__ hout2) {
    int i = blockIdx.x * 256 + threadIdx.x;
    if (i >= NN) return;
    const int b = i >> BSH, r = i & (BNODES - 1);
    const float di = dinv[i];
    float2 sv = ((const float2*)hin)[i];
    float a0 = sv.x, a1 = sv.y;
#pragma unroll
    for (int s = 0; s < SEG; ++s) {
        float2 p = ((const float2*)part)[((size_t)(b * SEG + s) << BSH) + r];
        a0 += p.x; a1 += p.y;
    }
    float h0 = tanhf(di * a0 + b4[0]);
    float h1 = tanhf(di * a1 + b4[1]);
    ((float2*)hout2)[i] = make_float2(h0, h1);
}

// Head: out[n,k] = h[n]·Wc[k] + bc[k]. One float4 (4 consecutive k) per thread.
__global__ __launch_bounds__(256) void k_f2(const float* __restrict__ h,
                                            const float* __restrict__ Wc,
                                            const float* __restrict__ bc,
                                            float* __restrict__ out) {
    int t = blockIdx.x * 256 + threadIdx.x;  // NN*28 units
    if (t >= NN * 28) return;
    int n = t / 28;
    int r = t - n * 28;
    int k = 4 * r;
    float2 hv = ((const float2*)h)[n];
    float4 o;
    o.x = fmaf(hv.y, Wc[2 * k + 1], fmaf(hv.x, Wc[2 * k + 0], bc[k + 0]));
    o.y = fmaf(hv.y, Wc[2 * k + 3], fmaf(hv.x, Wc[2 * k + 2], bc[k + 1]));
    o.z = fmaf(hv.y, Wc[2 * k + 5], fmaf(hv.x, Wc[2 * k + 4], bc[k + 2]));
    o.w = fmaf(hv.y, Wc[2 * k + 7], fmaf(hv.x, Wc[2 * k + 6], bc[k + 3]));
    ((float4*)out)[(size_t)n * 28 + r] = o;
}

// ================= fallback: R1 atomic-scatter path =================

__global__ __launch_bounds__(256) void k_init_deg(float* __restrict__ deg) {
    int i = blockIdx.x * 256 + threadIdx.x;
    if (i < NN) deg[i] = 1.0f;
}

__global__ __launch_bounds__(256) void k_count(const int* __restrict__ dst,
                                               float* __restrict__ deg) {
    int t = blockIdx.x * 256 + threadIdx.x;
    int4 d = ((const int4*)dst)[t];
    aadd(deg + d.x, 1.0f); aadd(deg + d.y, 1.0f);
    aadd(deg + d.z, 1.0f); aadd(deg + d.w, 1.0f);
}

__global__ __launch_bounds__(256) void k_dinv(float* __restrict__ deg) {
    int i = blockIdx.x * 256 + threadIdx.x;
    if (i < NN) deg[i] = 1.0f / sqrtf(deg[i]);
}

__global__ __launch_bounds__(256) void k_t1(const float* __restrict__ x,
                                            const float* __restrict__ W,
                                            const float* __restrict__ dinv,
                                            float* __restrict__ hp,
                                            float* __restrict__ ac) {
    int i = blockIdx.x * 256 + threadIdx.x;
    if (i >= NN) return;
    float4 x0 = ((const float4*)x)[2 * i];
    float4 x1 = ((const float4*)x)[2 * i + 1];
    float xi[8] = {x0.x, x0.y, x0.z, x0.w, x1.x, x1.y, x1.z, x1.w};
    float di = dinv[i];
    float o[4];
#pragma unroll
    for (int j = 0; j < 4; ++j) {
        float s = 0.f;
#pragma unroll
        for (int k = 0; k < 8; ++k) s = fmaf(xi[k], W[j * 8 + k], s);
        o[j] = di * s;
    }
    ((float4*)hp)[i] = make_float4(o[0], o[1], o[2], o[3]);
    ((float4*)ac)[i] = make_float4(0.f, 0.f, 0.f, 0.f);
}

__global__ __launch_bounds__(256) void k_s4(const int* __restrict__ src,
                                            const int* __restrict__ dst,
                                            const float* __restrict__ hp,
                                            float* __restrict__ ac) {
    int t = blockIdx.x * 256 + threadIdx.x;
    int4 s = ((const int4*)src)[t];
    int4 d = ((const int4*)dst)[t];
    float4 h;
    h = ((const float4*)hp)[s.x];
    aadd(ac + 4 * d.x + 0, h.x); aadd(ac + 4 * d.x + 1, h.y);
    aadd(ac + 4 * d.x + 2, h.z); aadd(ac + 4 * d.x + 3, h.w);
    h = ((const float4*)hp)[s.y];
    aadd(ac + 4 * d.y + 0, h.x); aadd(ac + 4 * d.y + 1, h.y);
    aadd(ac + 4 * d.y + 2, h.z); aadd(ac + 4 * d.y + 3, h.w);
    h = ((const float4*)hp)[s.z];
    aadd(ac + 4 * d.z + 0, h.x); aadd(ac + 4 * d.z + 1, h.y);
    aadd(ac + 4 * d.z + 2, h.z); aadd(ac + 4 * d.z + 3, h.w);
    h = ((const float4*)hp)[s.w];
    aadd(ac + 4 * d.w + 0, h.x); aadd(ac + 4 * d.w + 1, h.y);
    aadd(ac + 4 * d.w + 2, h.z); aadd(ac + 4 * d.w + 3, h.w);
}

__global__ __launch_bounds__(256) void k_s2(const int* __restrict__ src,
                                            const int* __restrict__ dst,
                                            const float* __restrict__ hp,
                                            float* __restrict__ ac) {
    int t = blockIdx.x * 256 + threadIdx.x;
    int4 s = ((const int4*)src)[t];
    int4 d = ((const int4*)dst)[t];
    float2 h;
    h = ((const float2*)hp)[s.x];
    aadd(ac + 2 * d.x + 0, h.x); aadd(ac + 2 * d.x + 1, h.y);
    h = ((const float2*)hp)[s.y];
    aadd(ac + 2 * d.y + 0, h.x); aadd(ac + 2 * d.y + 1, h.y);
    h = ((const float2*)hp)[s.z];
    aadd(ac + 2 * d.z + 0, h.x); aadd(ac + 2 * d.z + 1, h.y);
    h = ((const float2*)hp)[s.w];
    aadd(ac + 2 * d.w + 0, h.x); aadd(ac + 2 * d.w + 1, h.y);
}

template <bool RELU>
__global__ __launch_bounds__(256) void k_t44(const float* __restrict__ dinv,
                                             float* __restrict__ hp,
                                             float* __restrict__ ac,
                                             const float* __restrict__ bprev,
                                             const float* __restrict__ Wn) {
    int i = blockIdx.x * 256 + threadIdx.x;
    if (i >= NN) return;
    float di = dinv[i];
    float4 hv = ((const float4*)hp)[i];
    float4 av = ((const float4*)ac)[i];
    float h[4];
    h[0] = di * (av.x + hv.x) + bprev[0];
    h[1] = di * (av.y + hv.y) + bprev[1];
    h[2] = di * (av.z + hv.z) + bprev[2];
    h[3] = di * (av.w + hv.w) + bprev[3];
#pragma unroll
    for (int k = 0; k < 4; ++k) h[k] = RELU ? fmaxf(h[k], 0.f) : tanhf(h[k]);
    float o[4];
#pragma unroll
    for (int j = 0; j < 4; ++j) {
        float s = 0.f;
#pragma unroll
        for (int k = 0; k < 4; ++k) s = fmaf(h[k], Wn[j * 4 + k], s);
        o[j] = di * s;
    }
    ((float4*)hp)[i] = make_float4(o[0], o[1], o[2], o[3]);
    ((float4*)ac)[i] = make_float4(0.f, 0.f, 0.f, 0.f);
}

__global__ __launch_bounds__(256) void k_t42(const float* __restrict__ dinv,
                                             const float* __restrict__ hp4,
                                             const float* __restrict__ ac4,
                                             const float* __restrict__ bprev,
                                             const float* __restrict__ Wn,
                                             float* __restrict__ hp2,
                                             float* __restrict__ ac2) {
    int i = blockIdx.x * 256 + threadIdx.x;
    if (i >= NN) return;
    float di = dinv[i];
    float4 hv = ((const float4*)hp4)[i];
    float4 av = ((const float4*)ac4)[i];
    float h[4];
    h[0] = tanhf(di * (av.x + hv.x) + bprev[0]);
    h[1] = tanhf(di * (av.y + hv.y) + bprev[1]);
    h[2] = tanhf(di * (av.z + hv.z) + bprev[2]);
    h[3] = tanhf(di * (av.w + hv.w) + bprev[3]);
    float o0 = 0.f, o1 = 0.f;
#pragma unroll
    for (int k = 0; k < 4; ++k) {
        o0 = fmaf(h[k], Wn[k], o0);
        o1 = fmaf(h[k], Wn[4 + k], o1);
    }
    ((float2*)hp2)[i] = make_float2(di * o0, di * o1);
    ((float2*)ac2)[i] = make_float2(0.f, 0.f);
}

__global__ __launch_bounds__(256) void k_t22(const float* __restrict__ dinv,
                                             float* __restrict__ hp,
                                             float* __restrict__ ac,
                                             const float* __restrict__ bprev,
                                             const float* __restrict__ Wn) {
    int i = blockIdx.x * 256 + threadIdx.x;
    if (i >= NN) return;
    float di = dinv[i];
    float2 hv = ((const float2*)hp)[i];
    float2 av = ((const float2*)ac)[i];
    float h0 = fmaxf(di * (av.x + hv.x) + bprev[0], 0.f);
    float h1 = fmaxf(di * (av.y + hv.y) + bprev[1], 0.f);
    float o0 = fmaf(h1, Wn[1], h0 * Wn[0]);
    float o1 = fmaf(h1, Wn[3], h0 * Wn[2]);
    ((float2*)hp)[i] = make_float2(di * o0, di * o1);
    ((float2*)ac)[i] = make_float2(di * 0.f, di * 0.f);
}

__global__ __launch_bounds__(256) void k_f1(const float* __restrict__ dinv,
                                            const float* __restrict__ hp,
                                            float* __restrict__ ac,
                                            const float* __restrict__ b4,
                                            float* __restrict__ hout) {
    int i = blockIdx.x * 256 + threadIdx.x;
    if (i >= NN) return;
    float di = dinv[i];
    float2 hv = ((const float2*)hp)[i];
    float2 av = ((const float2*)ac)[i];
    float h0 = tanhf(di * (av.x + hv.x) + b4[0]);
    float h1 = tanhf(di * (av.y + hv.y) + b4[1]);
    ((float2*)hout)[i] = make_float2(h0, h1);
    ((float2*)ac)[i] = make_float2(h0, h1);
}

// ============================ launch ============================

extern "C" void kernel_launch(void* const* d_in, const int* in_sizes, int n_in,
                              void* d_out, int out_size, void* d_ws, size_t ws_size,
                              hipStream_t stream) {
    const float* x   = (const float*)d_in[0];
    const int*   ei  = (const int*)d_in[1];
    const int*   src = ei;
    const int*   dst = ei + NE;
    const float* W1 = (const float*)d_in[2];
    const float* b1 = (const float*)d_in[3];
    const float* W2 = (const float*)d_in[4];
    const float* b2 = (const float*)d_in[5];
    const float* W3 = (const float*)d_in[6];
    const float* b3 = (const float*)d_in[7];
    const float* W4 = (const float*)d_in[8];
    const float* b4 = (const float*)d_in[9];
    const float* Wc = (const float*)d_in[10];
    const float* bc = (const float*)d_in[11];
    float* out = (float*)d_out;
    float* hN2 = out + (size_t)112 * NN;   // second output chunk: h [N,2]

    const int NB_N  = (NN + 255) / 256;
    const int NB_E4 = NE / 4 / 256;        // 15625 exactly
    const int NB_F2 = (NN * 28 + 255) / 256;

    // workspace (u32 units): 13N h-buffers + tail(1024) + regoff(32768)
    //   + bins0 + bins1 + partial tiles
    const size_t binsz  = (size_t)NBK * BCAP;                 // 18,008,064
    const size_t part_f = (size_t)NBK * SEG * BNODES * 4;     // 4,001,792
    const size_t need_new =
        ((size_t)13 * NN + 1024 + 32768 + 2 * binsz + part_f) * 4;  // ~186.2 MB

    if (ws_size >= need_new) {
        // ---- region-sorted bucket-gather path ----
        float* ws   = (float*)d_ws;
        float* dinv = ws;                                  // N
        float* hpA  = ws + (size_t)NN;                     // 4N
        float* hpB  = ws + (size_t)5 * NN;                 // 4N
        float* h2A  = ws + (size_t)9 * NN;                 // 2N
        float* h2B  = ws + (size_t)11 * NN;                // 2N
        int*   tail = (int*)(ws + (size_t)13 * NN);        // NBK (pad 1024)
        int*   regoff = tail + 1024;                       // NBK*33 (pad 32768)
        unsigned* bins0 = (unsigned*)(regoff + 32768);     // NBK*BCAP
        unsigned* bins1 = bins0 + binsz;                   // NBK*BCAP
        float* part = (float*)(bins1 + binsz);             // partial tiles

        k_tinit<<<(NBK + 255) / 256, 256, 0, stream>>>(tail);
        k_binA<<<NBA, 256, 0, stream>>>(src, dst, tail, bins0);
        k_rebin<<<NBK, 256, 0, stream>>>(bins0, tail, bins1, regoff);
        g_degp<<<NBK * SEG, 256, 0, stream>>>(bins1, regoff, (int*)part);
        k_dinvp<<<NB_N, 256, 0, stream>>>((const int*)part, dinv);
        k_t1n<<<NB_N, 256, 0, stream>>>(x, W1, dinv, hpA);
        // conv1: gather partials + finish (relu,b1) + W2 transform
        g_part<4><<<NBK * SEG, 256, 0, stream>>>(bins1, regoff, hpA, part);
        k_finp<4, 4, true ><<<NB_N, 256, 0, stream>>>(part, dinv, hpA, b1, W2, hpB);
        // conv2: finish (tanh,b2) + W3 transform
        g_part<4><<<NBK * SEG, 256, 0, stream>>>(bins1, regoff, hpB, part);
        k_finp<4, 2, false><<<NB_N, 256, 0, stream>>>(part, dinv, hpB, b2, W3, h2A);
        // conv3: finish (relu,b3) + W4 transform
        g_part<2><<<NBK * SEG, 256, 0, stream>>>(bins1, regoff, h2A, part);
        k_finp<2, 2, true ><<<NB_N, 256, 0, stream>>>(part, dinv, h2A, b3, W4, h2B);
        // conv4: finish (tanh,b4) -> h, straight into out chunk
        g_part<2><<<NBK * SEG, 256, 0, stream>>>(bins1, regoff, h2B, part);
        k_flast<<<NB_N, 256, 0, stream>>>(part, dinv, h2B, b4, hN2);
        k_f2<<<NB_F2, 256, 0, stream>>>(hN2, Wc, bc, out);
    } else {
        // ---- fallback: R1 atomic-scatter path (passed @10.46 ms) ----
        float* ws   = (float*)d_ws;
        float* dinv = ws;
        float* hp4  = ws + (size_t)NN;
        float* ac4  = ws + (size_t)5 * NN;
        float* hp2  = ws + (size_t)9 * NN;
        float* ac2  = ws + (size_t)11 * NN;

        k_init_deg<<<NB_N, 256, 0, stream>>>(dinv);
        k_count<<<NB_E4, 256, 0, stream>>>(dst, dinv);
        k_dinv<<<NB_N, 256, 0, stream>>>(dinv);
        k_t1<<<NB_N, 256, 0, stream>>>(x, W1, dinv, hp4, ac4);
        k_s4<<<NB_E4, 256, 0, stream>>>(src, dst, hp4, ac4);
        k_t44<true><<<NB_N, 256, 0, stream>>>(dinv, hp4, ac4, b1, W2);
        k_s4<<<NB_E4, 256, 0, stream>>>(src, dst, hp4, ac4);
        k_t42<<<NB_N, 256, 0, stream>>>(dinv, hp4, ac4, b2, W3, hp2, ac2);
        k_s2<<<NB_E4, 256, 0, stream>>>(src, dst, hp2, ac2);
        k_t22<<<NB_N, 256, 0, stream>>>(dinv, hp2, ac2, b3, W4);
        k_s2<<<NB_E4, 256, 0, stream>>>(src, dst, hp2, ac2);
        k_f1<<<NB_N, 256, 0, stream>>>(dinv, hp2, ac2, b4, hN2);
        k_f2<<<NB_F2, 256, 0, stream>>>(ac2, Wc, bc, out);
    }
}

// Round 4
// 1462.344 us; speedup vs baseline: 1.2114x; 1.2114x over previous
//
#include <hip/hip_runtime.h>
#include <math.h>

// GCN_481036337415: 4-layer GCNConv (PyG norm w/ self-loops) + linear head.
// N=500000 nodes, E=16000000 edges. dims: 8 ->4 ->4 ->2 ->2 ->112.
//
// R1: device f32 atomics ~20 G/s -> atomic scatter = 10.5 ms.
// R2: padded bucket-CSR (k_fill 16M return-atomics = 1010 us) + per-node
//     register gathers (~225 us/layer) = 2.0 ms.
// R3: WG-binned buckets + per-bucket LDS-atomic gathers = 1.62 ms
//     (gathers 343 us @ 29% occ).
// R4: SEG=4 -> occ 72%, gathers still 343 us. Not latency/occupancy.
// R5: src-region sort -> FETCH 542->135 MB (L2-resident), gathers STILL
//     340 us. Invariant to occ, bytes, L2 residency; VALU <1%. Cost is
//     per-random-transaction in the TCP path, AND R2's LDS-free per-node
//     gather beat it (225 vs 340) -> the LDS atomics + sentinel branches
//     interleaved with loads are the overhead.
// R6 (this): cheap build (binA) + k_rebinC counting-sort by LOCAL DST ->
//     true CSR (4-aligned rows, node-indexed cnt/astart). Gather = R2
//     structure: thread-per-node, unroll-2 int4 groups (8 loads in
//     flight), no LDS, no branches in the hot loop, masked tail via
//     index-select, finish fully fused. No partial tiles, 6 fewer
//     launches.

constexpr int NN = 500000;
constexpr int NE = 16000000;

constexpr int BSH  = 9;                        // 512 nodes per bucket
constexpr int BNODES = 1 << BSH;               // 512
constexpr int NBK  = (NN + BNODES - 1) / BNODES;  // 977 buckets
constexpr int BCAP = 18432;                    // entries/bucket (mean 16376+~768 align pad, +10 sigma)
constexpr int ECHUNK = 16384;                  // edges per binning WG
constexpr int NBA = (NE + ECHUNK - 1) / ECHUNK;   // 977 WGs

__device__ __forceinline__ void aadd(float* p, float v) {
    unsafeAtomicAdd(p, v);
}

// ======================= CSR-bucket path =======================

__global__ __launch_bounds__(256) void k_tinit(int* __restrict__ tail) {
    int i = blockIdx.x * 256 + threadIdx.x;
    if (i < NBK) tail[i] = i * BCAP;
}

// Stage 1: two-pass WG binning by dst bucket. Pass1: LDS bucket histogram.
// Reserve: one global atomicAdd per (WG,bucket). Pass2: LDS re-rank +
// packed write (local_dst<<19 | src), runs of ~17 entries -> line-efficient.
__global__ __launch_bounds__(256) void k_binA(const int* __restrict__ src,
                                              const int* __restrict__ dst,
                                              int* __restrict__ tail,
                                              unsigned* __restrict__ bins) {
    __shared__ int cnt[NBK];
    __shared__ int bbase[NBK];
    const int t = threadIdx.x;
    for (int k = t; k < NBK; k += 256) cnt[k] = 0;
    __syncthreads();

    const long e0 = (long)blockIdx.x * ECHUNK;
    const int ne = (int)min((long)ECHUNK, (long)NE - e0);
    const int g0 = (int)(e0 >> 2);
    const int ng = ne >> 2;  // chunk%4==0 -> exact

    for (int g = t; g < ng; g += 256) {
        int4 d = ((const int4*)dst)[g0 + g];
        atomicAdd(&cnt[d.x >> BSH], 1);
        atomicAdd(&cnt[d.y >> BSH], 1);
        atomicAdd(&cnt[d.z >> BSH], 1);
        atomicAdd(&cnt[d.w >> BSH], 1);
    }
    __syncthreads();
    for (int k = t; k < NBK; k += 256) {
        int c = cnt[k];
        bbase[k] = c ? atomicAdd(&tail[k], c) : 0;
        cnt[k] = 0;
    }
    __syncthreads();
    for (int g = t; g < ng; g += 256) {
        int4 d = ((const int4*)dst)[g0 + g];
        int4 s = ((const int4*)src)[g0 + g];
        int b, r, idx;
        b = d.x >> BSH; r = atomicAdd(&cnt[b], 1); idx = bbase[b] + r;
        if (idx < (b + 1) * BCAP)
            bins[idx] = ((unsigned)(d.x & (BNODES - 1)) << 19) | (unsigned)s.x;
        b = d.y >> BSH; r = atomicAdd(&cnt[b], 1); idx = bbase[b] + r;
        if (idx < (b + 1) * BCAP)
            bins[idx] = ((unsigned)(d.y & (BNODES - 1)) << 19) | (unsigned)s.y;
        b = d.z >> BSH; r = atomicAdd(&cnt[b], 1); idx = bbase[b] + r;
        if (idx < (b + 1) * BCAP)
            bins[idx] = ((unsigned)(d.z & (BNODES - 1)) << 19) | (unsigned)s.z;
        b = d.w >> BSH; r = atomicAdd(&cnt[b], 1); idx = bbase[b] + r;
        if (idx < (b + 1) * BCAP)
            bins[idx] = ((unsigned)(d.w & (BNODES - 1)) << 19) | (unsigned)s.w;
    }
}

// Stage 2: per-bucket counting sort by LOCAL DST -> CSR with 4-aligned
// rows. Emits node-indexed cnt[] (true degree) and astart[] (absolute
// 4-aligned row start). Scatter stays inside the bucket's 72KB window.
__global__ __launch_bounds__(256) void k_rebinC(const unsigned* __restrict__ bins0,
                                                const int* __restrict__ tail,
                                                unsigned* __restrict__ bins1,
                                                int* __restrict__ astart,
                                                int* __restrict__ cnt) {
    __shared__ int c1[BNODES];   // histogram
    __shared__ int wb[BNODES];   // aligned local row starts
    __shared__ int c2[BNODES];   // scatter ranks
    const int b = blockIdx.x;
    const int t = threadIdx.x;
    c1[t] = 0; c1[t + 256] = 0;
    c2[t] = 0; c2[t + 256] = 0;
    __syncthreads();
    const int base = b * BCAP;
    const int n = min(tail[b] - base, BCAP);
    const unsigned* e0 = bins0 + base;
    for (int j = t; j < n; j += 256) atomicAdd(&c1[e0[j] >> 19], 1);
    __syncthreads();
    if (t == 0) {
        int o = 0;
        for (int r = 0; r < BNODES; ++r) {
            wb[r] = o;
            o = (o + c1[r] + 3) & ~3;  // 4-align each row
        }
    }
    __syncthreads();
    const int nb = b << BSH;
    cnt[nb + t] = c1[t];
    cnt[nb + t + 256] = c1[t + 256];
    astart[nb + t] = base + wb[t];
    astart[nb + t + 256] = base + wb[t + 256];
    for (int j = t; j < n; j += 256) {
        unsigned v = e0[j];
        int l = v >> 19;
        int k = atomicAdd(&c2[l], 1);
        int idx = wb[l] + k;
        if (idx < BCAP) bins1[base + idx] = v & 0x7FFFFu;
    }
}

// T1: dinv = rsqrt(deg+1) (fused), hp = dinv * (x @ W1.T)
__global__ __launch_bounds__(256) void k_t1n(const float* __restrict__ x,
                                             const float* __restrict__ W,
                                             const int* __restrict__ cnt,
                                             float* __restrict__ dinv,
                                             float* __restrict__ hp) {
    int i = blockIdx.x * 256 + threadIdx.x;
    if (i >= NN) return;
    float4 x0 = ((const float4*)x)[2 * i];
    float4 x1 = ((const float4*)x)[2 * i + 1];
    float xi[8] = {x0.x, x0.y, x0.z, x0.w, x1.x, x1.y, x1.z, x1.w};
    float di = rsqrtf((float)cnt[i] + 1.0f);  // +1 self-loop
    dinv[i] = di;
    float o[4];
#pragma unroll
    for (int j = 0; j < 4; ++j) {
        float s = 0.f;
#pragma unroll
        for (int k = 0; k < 8; ++k) s = fmaf(xi[k], W[j * 8 + k], s);
        o[j] = di * s;
    }
    ((float4*)hp)[i] = make_float4(o[0], o[1], o[2], o[3]);
}

// Per-node CSR gather + fused finish: register accumulation over the
// node's contiguous src row (int4 groups, unroll-2 -> 8 loads in flight),
// no LDS, no hot-loop branches; tail group via index-select + weight.
template <int IND, int OUTD, bool RELU>
__global__ __launch_bounds__(256) void g_csr(const int* __restrict__ astart,
                                             const int* __restrict__ cnt,
                                             const unsigned* __restrict__ bins,
                                             const float* __restrict__ dinv,
                                             const float* __restrict__ hin,
                                             const float* __restrict__ bp,
                                             const float* __restrict__ Wn,
                                             float* __restrict__ hout) {
    int i = blockIdx.x * 256 + threadIdx.x;
    if (i >= NN) return;
    const int cn = cnt[i];
    const uint4* rp = (const uint4*)bins + (astart[i] >> 2);
    float acc[IND];
    if constexpr (IND == 4) {
        float4 sv = ((const float4*)hin)[i];
        acc[0] = sv.x; acc[1] = sv.y; acc[2] = sv.z; acc[3] = sv.w;
    } else {
        float2 sv = ((const float2*)hin)[i];
        acc[0] = sv.x; acc[1] = sv.y;
    }
    const int full = cn >> 2, rem = cn & 3;
    int j = 0;
    for (; j + 2 <= full; j += 2) {
        uint4 a = rp[j], c = rp[j + 1];
        if constexpr (IND == 4) {
            float4 h0 = ((const float4*)hin)[a.x];
            float4 h1 = ((const float4*)hin)[a.y];
            float4 h2 = ((const float4*)hin)[a.z];
            float4 h3 = ((const float4*)hin)[a.w];
            float4 h4 = ((const float4*)hin)[c.x];
            float4 h5 = ((const float4*)hin)[c.y];
            float4 h6 = ((const float4*)hin)[c.z];
            float4 h7 = ((const float4*)hin)[c.w];
            acc[0] += ((h0.x + h1.x) + (h2.x + h3.x)) + ((h4.x + h5.x) + (h6.x + h7.x));
            acc[1] += ((h0.y + h1.y) + (h2.y + h3.y)) + ((h4.y + h5.y) + (h6.y + h7.y));
            acc[2] += ((h0.z + h1.z) + (h2.z + h3.z)) + ((h4.z + h5.z) + (h6.z + h7.z));
            acc[3] += ((h0.w + h1.w) + (h2.w + h3.w)) + ((h4.w + h5.w) + (h6.w + h7.w));
        } else {
            float2 h0 = ((const float2*)hin)[a.x];
            float2 h1 = ((const float2*)hin)[a.y];
            float2 h2 = ((const float2*)hin)[a.z];
            float2 h3 = ((const float2*)hin)[a.w];
            float2 h4 = ((const float2*)hin)[c.x];
            float2 h5 = ((const float2*)hin)[c.y];
            float2 h6 = ((const float2*)hin)[c.z];
            float2 h7 = ((const float2*)hin)[c.w];
            acc[0] += ((h0.x + h1.x) + (h2.x + h3.x)) + ((h4.x + h5.x) + (h6.x + h7.x));
            acc[1] += ((h0.y + h1.y) + (h2.y + h3.y)) + ((h4.y + h5.y) + (h6.y + h7.y));
        }
    }
    if (j < full) {
        uint4 a = rp[j];
        if constexpr (IND == 4) {
            float4 h0 = ((const float4*)hin)[a.x];
            float4 h1 = ((const float4*)hin)[a.y];
            float4 h2 = ((const float4*)hin)[a.z];
            float4 h3 = ((const float4*)hin)[a.w];
            acc[0] += (h0.x + h1.x) + (h2.x + h3.x);
            acc[1] += (h0.y + h1.y) + (h2.y + h3.y);
            acc[2] += (h0.z + h1.z) + (h2.z + h3.z);
            acc[3] += (h0.w + h1.w) + (h2.w + h3.w);
        } else {
            float2 h0 = ((const float2*)hin)[a.x];
            float2 h1 = ((const float2*)hin)[a.y];
            float2 h2 = ((const float2*)hin)[a.z];
            float2 h3 = ((const float2*)hin)[a.w];
            acc[0] += (h0.x + h1.x) + (h2.x + h3.x);
            acc[1] += (h0.y + h1.y) + (h2.y + h3.y);
        }
    }
    if (rem) {
        uint4 a = rp[full];
        unsigned s1 = rem > 1 ? a.y : a.x;
        unsigned s2 = rem > 2 ? a.z : a.x;
        float w1 = rem > 1 ? 1.f : 0.f;
        float w2 = rem > 2 ? 1.f : 0.f;
        if constexpr (IND == 4) {
            float4 h0 = ((const float4*)hin)[a.x];
            float4 h1 = ((const float4*)hin)[s1];
            float4 h2 = ((const float4*)hin)[s2];
            acc[0] += h0.x + w1 * h1.x + w2 * h2.x;
            acc[1] += h0.y + w1 * h1.y + w2 * h2.y;
            acc[2] += h0.z + w1 * h1.z + w2 * h2.z;
            acc[3] += h0.w + w1 * h1.w + w2 * h2.w;
        } else {
            float2 h0 = ((const float2*)hin)[a.x];
            float2 h1 = ((const float2*)hin)[s1];
            float2 h2 = ((const float2*)hin)[s2];
            acc[0] += h0.x + w1 * h1.x + w2 * h2.x;
            acc[1] += h0.y + w1 * h1.y + w2 * h2.y;
        }
    }
    const float di = dinv[i];
    float h[IND];
#pragma unroll
    for (int k = 0; k < IND; ++k) {
        float v = di * acc[k] + bp[k];
        h[k] = RELU ? fmaxf(v, 0.f) : tanhf(v);
    }
    float o[OUTD];
#pragma unroll
    for (int q = 0; q < OUTD; ++q) {
        float s = 0.f;
#pragma unroll
        for (int k = 0; k < IND; ++k) s = fmaf(h[k], Wn[q * IND + k], s);
        o[q] = di * s;
    }
    if constexpr (OUTD == 4)
        ((float4*)hout)[i] = make_float4(o[0], o[1], o[2], o[3]);
    else
        ((float2*)hout)[i] = make_float2(o[0], o[1]);
}

// Final gather: finish conv4 (tanh,b4) -> h[N,2] straight into out chunk.
__global__ __launch_bounds__(256) void g_csrF(const int* __restrict__ astart,
                                              const int* __restrict__ cnt,
                                              const unsigned* __restrict__ bins,
                                              const float* __restrict__ dinv,
                                              const float* __restrict__ hin,
                                              const float* __restrict__ b4,
                                              float* __restrict__ hout2) {
    int i = blockIdx.x * 256 + threadIdx.x;
    if (i >= NN) return;
    const int cn = cnt[i];
    const uint4* rp = (const uint4*)bins + (astart[i] >> 2);
    float2 sv = ((const float2*)hin)[i];
    float a0 = sv.x, a1 = sv.y;
    const int full = cn >> 2, rem = cn & 3;
    int j = 0;
    for (; j + 2 <= full; j += 2) {
        uint4 a = rp[j], c = rp[j + 1];
        float2 h0 = ((const float2*)hin)[a.x];
        float2 h1 = ((const float2*)hin)[a.y];
        float2 h2 = ((const float2*)hin)[a.z];
        float2 h3 = ((const float2*)hin)[a.w];
        float2 h4 = ((const float2*)hin)[c.x];
        float2 h5 = ((const float2*)hin)[c.y];
        float2 h6 = ((const float2*)hin)[c.z];
        float2 h7 = ((const float2*)hin)[c.w];
        a0 += ((h0.x + h1.x) + (h2.x + h3.x)) + ((h4.x + h5.x) + (h6.x + h7.x));
        a1 += ((h0.y + h1.y) + (h2.y + h3.y)) + ((h4.y + h5.y) + (h6.y + h7.y));
    }
    if (j < full) {
        uint4 a = rp[j];
        float2 h0 = ((const float2*)hin)[a.x];
        float2 h1 = ((const float2*)hin)[a.y];
        float2 h2 = ((const float2*)hin)[a.z];
        float2 h3 = ((const float2*)hin)[a.w];
        a0 += (h0.x + h1.x) + (h2.x + h3.x);
        a1 += (h0.y + h1.y) + (h2.y + h3.y);
    }
    if (rem) {
        uint4 a = rp[full];
        unsigned s1 = rem > 1 ? a.y : a.x;
        unsigned s2 = rem > 2 ? a.z : a.x;
        float w1 = rem > 1 ? 1.f : 0.f;
        float w2 = rem > 2 ? 1.f : 0.f;
        float2 h0 = ((const float2*)hin)[a.x];
        float2 h1 = ((const float2*)hin)[s1];
        float2 h2 = ((const float2*)hin)[s2];
        a0 += h0.x + w1 * h1.x + w2 * h2.x;
        a1 += h0.y + w1 * h1.y + w2 * h2.y;
    }
    const float di = dinv[i];
    float h0 = tanhf(di * a0 + b4[0]);
    float h1 = tanhf(di * a1 + b4[1]);
    ((float2*)hout2)[i] = make_float2(h0, h1);
}

// Head: out[n,k] = h[n]·Wc[k] + bc[k]. One float4 (4 consecutive k) per thread.
__global__ __launch_bounds__(256) void k_f2(const float* __restrict__ h,
                                            const float* __restrict__ Wc,
                                            const float* __restrict__ bc,
                                            float* __restrict__ out) {
    int t = blockIdx.x * 256 + threadIdx.x;  // NN*28 units
    if (t >= NN * 28) return;
    int n = t / 28;
    int r = t - n * 28;
    int k = 4 * r;
    float2 hv = ((const float2*)h)[n];
    float4 o;
    o.x = fmaf(hv.y, Wc[2 * k + 1], fmaf(hv.x, Wc[2 * k + 0], bc[k + 0]));
    o.y = fmaf(hv.y, Wc[2 * k + 3], fmaf(hv.x, Wc[2 * k + 2], bc[k + 1]));
    o.z = fmaf(hv.y, Wc[2 * k + 5], fmaf(hv.x, Wc[2 * k + 4], bc[k + 2]));
    o.w = fmaf(hv.y, Wc[2 * k + 7], fmaf(hv.x, Wc[2 * k + 6], bc[k + 3]));
    ((float4*)out)[(size_t)n * 28 + r] = o;
}

// ================= fallback: R1 atomic-scatter path =================

__global__ __launch_bounds__(256) void k_init_deg(float* __restrict__ deg) {
    int i = blockIdx.x * 256 + threadIdx.x;
    if (i < NN) deg[i] = 1.0f;
}

__global__ __launch_bounds__(256) void k_count(const int* __restrict__ dst,
                                               float* __restrict__ deg) {
    int t = blockIdx.x * 256 + threadIdx.x;
    int4 d = ((const int4*)dst)[t];
    aadd(deg + d.x, 1.0f); aadd(deg + d.y, 1.0f);
    aadd(deg + d.z, 1.0f); aadd(deg + d.w, 1.0f);
}

__global__ __launch_bounds__(256) void k_dinv(float* __restrict__ deg) {
    int i = blockIdx.x * 256 + threadIdx.x;
    if (i < NN) deg[i] = 1.0f / sqrtf(deg[i]);
}

__global__ __launch_bounds__(256) void k_t1(const float* __restrict__ x,
                                            const float* __restrict__ W,
                                            const float* __restrict__ dinv,
                                            float* __restrict__ hp,
                                            float* __restrict__ ac) {
    int i = blockIdx.x * 256 + threadIdx.x;
    if (i >= NN) return;
    float4 x0 = ((const float4*)x)[2 * i];
    float4 x1 = ((const float4*)x)[2 * i + 1];
    float xi[8] = {x0.x, x0.y, x0.z, x0.w, x1.x, x1.y, x1.z, x1.w};
    float di = dinv[i];
    float o[4];
#pragma unroll
    for (int j = 0; j < 4; ++j) {
        float s = 0.f;
#pragma unroll
        for (int k = 0; k < 8; ++k) s = fmaf(xi[k], W[j * 8 + k], s);
        o[j] = di * s;
    }
    ((float4*)hp)[i] = make_float4(o[0], o[1], o[2], o[3]);
    ((float4*)ac)[i] = make_float4(0.f, 0.f, 0.f, 0.f);
}

__global__ __launch_bounds__(256) void k_s4(const int* __restrict__ src,
                                            const int* __restrict__ dst,
                                            const float* __restrict__ hp,
                                            float* __restrict__ ac) {
    int t = blockIdx.x * 256 + threadIdx.x;
    int4 s = ((const int4*)src)[t];
    int4 d = ((const int4*)dst)[t];
    float4 h;
    h = ((const float4*)hp)[s.x];
    aadd(ac + 4 * d.x + 0, h.x); aadd(ac + 4 * d.x + 1, h.y);
    aadd(ac + 4 * d.x + 2, h.z); aadd(ac + 4 * d.x + 3, h.w);
    h = ((const float4*)hp)[s.y];
    aadd(ac + 4 * d.y + 0, h.x); aadd(ac + 4 * d.y + 1, h.y);
    aadd(ac + 4 * d.y + 2, h.z); aadd(ac + 4 * d.y + 3, h.w);
    h = ((const float4*)hp)[s.z];
    aadd(ac + 4 * d.z + 0, h.x); aadd(ac + 4 * d.z + 1, h.y);
    aadd(ac + 4 * d.z + 2, h.z); aadd(ac + 4 * d.z + 3, h.w);
    h = ((const float4*)hp)[s.w];
    aadd(ac + 4 * d.w + 0, h.x); aadd(ac + 4 * d.w + 1, h.y);
    aadd(ac + 4 * d.w + 2, h.z); aadd(ac + 4 * d.w + 3, h.w);
}

__global__ __launch_bounds__(256) void k_s2(const int* __restrict__ src,
                                            const int* __restrict__ dst,
                                            const float* __restrict__ hp,
                                            float* __restrict__ ac) {
    int t = blockIdx.x * 256 + threadIdx.x;
    int4 s = ((const int4*)src)[t];
    int4 d = ((const int4*)dst)[t];
    float2 h;
    h = ((const float2*)hp)[s.x];
    aadd(ac + 2 * d.x + 0, h.x); aadd(ac + 2 * d.x + 1, h.y);
    h = ((const float2*)hp)[s.y];
    aadd(ac + 2 * d.y + 0, h.x); aadd(ac + 2 * d.y + 1, h.y);
    h = ((const float2*)hp)[s.z];
    aadd(ac + 2 * d.z + 0, h.x); aadd(ac + 2 * d.z + 1, h.y);
    h = ((const float2*)hp)[s.w];
    aadd(ac + 2 * d.w + 0, h.x); aadd(ac + 2 * d.w + 1, h.y);
}

template <bool RELU>
__global__ __launch_bounds__(256) void k_t44(const float* __restrict__ dinv,
                                             float* __restrict__ hp,
                                             float* __restrict__ ac,
                                             const float* __restrict__ bprev,
                                             const float* __restrict__ Wn) {
    int i = blockIdx.x * 256 + threadIdx.x;
    if (i >= NN) return;
    float di = dinv[i];
    float4 hv = ((const float4*)hp)[i];
    float4 av = ((const float4*)ac)[i];
    float h[4];
    h[0] = di * (av.x + hv.x) + bprev[0];
    h[1] = di * (av.y + hv.y) + bprev[1];
    h[2] = di * (av.z + hv.z) + bprev[2];
    h[3] = di * (av.w + hv.w) + bprev[3];
#pragma unroll
    for (int k = 0; k < 4; ++k) h[k] = RELU ? fmaxf(h[k], 0.f) : tanhf(h[k]);
    float o[4];
#pragma unroll
    for (int j = 0; j < 4; ++j) {
        float s = 0.f;
#pragma unroll
        for (int k = 0; k < 4; ++k) s = fmaf(h[k], Wn[j * 4 + k], s);
        o[j] = di * s;
    }
    ((float4*)hp)[i] = make_float4(o[0], o[1], o[2], o[3]);
    ((float4*)ac)[i] = make_float4(0.f, 0.f, 0.f, 0.f);
}

__global__ __launch_bounds__(256) void k_t42(const float* __restrict__ dinv,
                                             const float* __restrict__ hp4,
                                             const float* __restrict__ ac4,
                                             const float* __restrict__ bprev,
                                             const float* __restrict__ Wn,
                                             float* __restrict__ hp2,
                                             float* __restrict__ ac2) {
    int i = blockIdx.x * 256 + threadIdx.x;
    if (i >= NN) return;
    float di = dinv[i];
    float4 hv = ((const float4*)hp4)[i];
    float4 av = ((const float4*)ac4)[i];
    float h[4];
    h[0] = tanhf(di * (av.x + hv.x) + bprev[0]);
    h[1] = tanhf(di * (av.y + hv.y) + bprev[1]);
    h[2] = tanhf(di * (av.z + hv.z) + bprev[2]);
    h[3] = tanhf(di * (av.w + hv.w) + bprev[3]);
    float o0 = 0.f, o1 = 0.f;
#pragma unroll
    for (int k = 0; k < 4; ++k) {
        o0 = fmaf(h[k], Wn[k], o0);
        o1 = fmaf(h[k], Wn[4 + k], o1);
    }
    ((float2*)hp2)[i] = make_float2(di * o0, di * o1);
    ((float2*)ac2)[i] = make_float2(0.f, 0.f);
}

__global__ __launch_bounds__(256) void k_t22(const float* __restrict__ dinv,
                                             float* __restrict__ hp,
                                             float* __restrict__ ac,
                                             const float* __restrict__ bprev,
                                             const float* __restrict__ Wn) {
    int i = blockIdx.x * 256 + threadIdx.x;
    if (i >= NN) return;
    float di = dinv[i];
    float2 hv = ((const float2*)hp)[i];
    float2 av = ((const float2*)ac)[i];
    float h0 = fmaxf(di * (av.x + hv.x) + bprev[0], 0.f);
    float h1 = fmaxf(di * (av.y + hv.y) + bprev[1], 0.f);
    float o0 = fmaf(h1, Wn[1], h0 * Wn[0]);
    float o1 = fmaf(h1, Wn[3], h0 * Wn[2]);
    ((float2*)hp)[i] = make_float2(di * o0, di * o1);
    ((float2*)ac)[i] = make_float2(di * 0.f, di * 0.f);
}

__global__ __launch_bounds__(256) void k_f1(const float* __restrict__ dinv,
                                            const float* __restrict__ hp,
                                            float* __restrict__ ac,
                                            const float* __restrict__ b4,
                                            float* __restrict__ hout) {
    int i = blockIdx.x * 256 + threadIdx.x;
    if (i >= NN) return;
    float di = dinv[i];
    float2 hv = ((const float2*)hp)[i];
    float2 av = ((const float2*)ac)[i];
    float h0 = tanhf(di * (av.x + hv.x) + b4[0]);
    float h1 = tanhf(di * (av.y + hv.y) + b4[1]);
    ((float2*)hout)[i] = make_float2(h0, h1);
    ((float2*)ac)[i] = make_float2(h0, h1);
}

// ============================ launch ============================

extern "C" void kernel_launch(void* const* d_in, const int* in_sizes, int n_in,
                              void* d_out, int out_size, void* d_ws, size_t ws_size,
                              hipStream_t stream) {
    const float* x   = (const float*)d_in[0];
    const int*   ei  = (const int*)d_in[1];
    const int*   src = ei;
    const int*   dst = ei + NE;
    const float* W1 = (const float*)d_in[2];
    const float* b1 = (const float*)d_in[3];
    const float* W2 = (const float*)d_in[4];
    const float* b2 = (const float*)d_in[5];
    const float* W3 = (const float*)d_in[6];
    const float* b3 = (const float*)d_in[7];
    const float* W4 = (const float*)d_in[8];
    const float* b4 = (const float*)d_in[9];
    const float* Wc = (const float*)d_in[10];
    const float* bc = (const float*)d_in[11];
    float* out = (float*)d_out;
    float* hN2 = out + (size_t)112 * NN;   // second output chunk: h [N,2]

    const int NB_N  = (NN + 255) / 256;
    const int NB_E4 = NE / 4 / 256;        // 15625 exactly
    const int NB_F2 = (NN * 28 + 255) / 256;

    // workspace (u32 units): 13N h-buffers + tail(1024) + cnt + astart
    //   + bins0 + bins1
    const size_t binsz = (size_t)NBK * BCAP;            // 18,008,064
    const size_t nodesz = (size_t)NBK << BSH;           // 500,224
    const size_t need_new =
        ((size_t)13 * NN + 1024 + 2 * nodesz + 2 * binsz) * 4;  // ~174 MB

    if (ws_size >= need_new) {
        // ---- CSR-bucket register-gather path ----
        float* ws   = (float*)d_ws;
        float* dinv = ws;                                  // N
        float* hpA  = ws + (size_t)NN;                     // 4N
        float* hpB  = ws + (size_t)5 * NN;                 // 4N
        float* h2A  = ws + (size_t)9 * NN;                 // 2N
        float* h2B  = ws + (size_t)11 * NN;                // 2N
        int*   tail = (int*)(ws + (size_t)13 * NN);        // NBK (pad 1024)
        int*   cntA = tail + 1024;                         // node-indexed deg
        int*   astart = cntA + nodesz;                     // node-indexed row start
        unsigned* bins0 = (unsigned*)(astart + nodesz);    // NBK*BCAP
        unsigned* bins1 = bins0 + binsz;                   // NBK*BCAP (CSR)

        k_tinit<<<(NBK + 255) / 256, 256, 0, stream>>>(tail);
        k_binA<<<NBA, 256, 0, stream>>>(src, dst, tail, bins0);
        k_rebinC<<<NBK, 256, 0, stream>>>(bins0, tail, bins1, astart, cntA);
        k_t1n<<<NB_N, 256, 0, stream>>>(x, W1, cntA, dinv, hpA);
        // conv1 finish (relu,b1) + W2 transform
        g_csr<4, 4, true ><<<NB_N, 256, 0, stream>>>(astart, cntA, bins1, dinv, hpA, b1, W2, hpB);
        // conv2 finish (tanh,b2) + W3 transform
        g_csr<4, 2, false><<<NB_N, 256, 0, stream>>>(astart, cntA, bins1, dinv, hpB, b2, W3, h2A);
        // conv3 finish (relu,b3) + W4 transform
        g_csr<2, 2, true ><<<NB_N, 256, 0, stream>>>(astart, cntA, bins1, dinv, h2A, b3, W4, h2B);
        // conv4 finish (tanh,b4) -> h, straight into out chunk
        g_csrF<<<NB_N, 256, 0, stream>>>(astart, cntA, bins1, dinv, h2B, b4, hN2);
        k_f2<<<NB_F2, 256, 0, stream>>>(hN2, Wc, bc, out);
    } else {
        // ---- fallback: R1 atomic-scatter path (passed @10.46 ms) ----
        float* ws   = (float*)d_ws;
        float* dinv = ws;
        float* hp4  = ws + (size_t)NN;
        float* ac4  = ws + (size_t)5 * NN;
        float* hp2  = ws + (size_t)9 * NN;
        float* ac2  = ws + (size_t)11 * NN;

        k_init_deg<<<NB_N, 256, 0, stream>>>(dinv);
        k_count<<<NB_E4, 256, 0, stream>>>(dst, dinv);
        k_dinv<<<NB_N, 256, 0, stream>>>(dinv);
        k_t1<<<NB_N, 256, 0, stream>>>(x, W1, dinv, hp4, ac4);
        k_s4<<<NB_E4, 256, 0, stream>>>(src, dst, hp4, ac4);
        k_t44<true><<<NB_N, 256, 0, stream>>>(dinv, hp4, ac4, b1, W2);
        k_s4<<<NB_E4, 256, 0, stream>>>(src, dst, hp4, ac4);
        k_t42<<<NB_N, 256, 0, stream>>>(dinv, hp4, ac4, b2, W3, hp2, ac2);
        k_s2<<<NB_E4, 256, 0, stream>>>(src, dst, hp2, ac2);
        k_t22<<<NB_N, 256, 0, stream>>>(dinv, hp2, ac2, b3, W4);
        k_s2<<<NB_E4, 256, 0, stream>>>(src, dst, hp2, ac2);
        k_f1<<<NB_N, 256, 0, stream>>>(dinv, hp2, ac2, b4, hN2);
        k_f2<<<NB_F2, 256, 0, stream>>>(ac2, Wc, bc, out);
    }
}

// Round 5
// 1173.843 us; speedup vs baseline: 1.5091x; 1.2458x over previous
//
#include <hip/hip_runtime.h>
#include <math.h>

// GCN_481036337415: 4-layer GCNConv (PyG norm w/ self-loops) + linear head.
// N=500000 nodes, E=16000000 edges. dims: 8 ->4 ->4 ->2 ->2 ->112.
//
// R1: device f32 atomics ~20 G/s -> atomic scatter = 10.5 ms.
// R2: padded bucket-CSR (k_fill 16M return-atomics = 1010 us) = 2.0 ms.
// R3-R5: WG-binned buckets + LDS-atomic gathers: gathers pinned at 343 us
//     regardless of occupancy (29->72%), FETCH (542->135 MB), L2 residency
//     -> per-random-transaction wall + LDS overhead.
// R6: register-gather CSR (thread/node, 8 loads in flight) = 1.46 ms.
//     Gathers ~230/layer. NEW #1: k_binA 336 us = 16M scattered 4B stores
//     at the same ~21 ns*chip/edge transaction wall (WRITE 434 MB, 6.8x
//     amplification; runs filled temporally-scattered -> cold lines).
//     rebinC (~200 us) has the same in-window scattered-store pattern.
// R7 (this): burst the build stores.
//     k_binB: LDS chunk-sort (hist -> shfl-scan -> LDS scatter), then
//       stream out: consecutive threads -> consecutive run addresses.
//       16M scattered stores -> ~2M coalesced transactions. 98KB dyn LDS.
//     k_rebinD: stage dst-sorted CSR in 72KB dyn LDS, write bins1 as one
//       coalesced uint4 stream. Parallel shfl-scan prefix.
//     Runtime fallback to R6 kernels if dynamic-LDS attribute fails.

constexpr int NN = 500000;
constexpr int NE = 16000000;

constexpr int BSH  = 9;                        // 512 nodes per bucket
constexpr int BNODES = 1 << BSH;               // 512
constexpr int NBK  = (NN + BNODES - 1) / BNODES;  // 977 buckets
constexpr int BCAP = 18432;                    // entries/bucket (mean 16376+align pad)
constexpr int ECHUNK = 16384;                  // edges per binning WG
constexpr int NBA = (NE + ECHUNK - 1) / ECHUNK;   // 977 WGs
constexpr int DYN_BINB  = ECHUNK * 4 + ECHUNK * 2;  // 98304 B (chunk + bid)
constexpr int DYN_REBIN = BCAP * 4;                 // 73728 B

__device__ __forceinline__ void aadd(float* p, float v) {
    unsafeAtomicAdd(p, v);
}

// ======================= CSR-bucket path =======================

__global__ __launch_bounds__(256) void k_tinit(int* __restrict__ tail) {
    int i = blockIdx.x * 256 + threadIdx.x;
    if (i < NBK) tail[i] = i * BCAP;
}

// -------- Stage 1 (R7): LDS chunk-sort + burst write --------
__global__ __launch_bounds__(256) void k_binB(const int* __restrict__ src,
                                              const int* __restrict__ dst,
                                              int* __restrict__ tail,
                                              unsigned* __restrict__ bins) {
    extern __shared__ unsigned dynbuf[];
    unsigned* chunk = dynbuf;                                   // ECHUNK u32
    unsigned short* bid = (unsigned short*)(dynbuf + ECHUNK);   // ECHUNK u16
    __shared__ int c1[NBK];
    __shared__ int lofs[NBK];
    __shared__ int dlt[NBK];
    __shared__ int wsum[4];
    const int t = threadIdx.x;
    for (int k = t; k < NBK; k += 256) c1[k] = 0;
    __syncthreads();

    const long e0l = (long)blockIdx.x * ECHUNK;
    const int ne = (int)min((long)ECHUNK, (long)NE - e0l);
    const int g0 = (int)(e0l >> 2);
    const int ng = ne >> 2;  // NE%4==0, ECHUNK%4==0 -> exact

    // pass 1: LDS histogram over buckets
    for (int g = t; g < ng; g += 256) {
        int4 d = ((const int4*)dst)[g0 + g];
        atomicAdd(&c1[d.x >> BSH], 1);
        atomicAdd(&c1[d.y >> BSH], 1);
        atomicAdd(&c1[d.z >> BSH], 1);
        atomicAdd(&c1[d.w >> BSH], 1);
    }
    __syncthreads();
    // exclusive prefix scan (977 values; thread t covers [4t,4t+4))
    int b0 = 4 * t;
    int v0 = b0 + 0 < NBK ? c1[b0 + 0] : 0;
    int v1 = b0 + 1 < NBK ? c1[b0 + 1] : 0;
    int v2 = b0 + 2 < NBK ? c1[b0 + 2] : 0;
    int v3 = b0 + 3 < NBK ? c1[b0 + 3] : 0;
    int loc = v0 + v1 + v2 + v3, inc = loc;
#pragma unroll
    for (int d = 1; d < 64; d <<= 1) {
        int u = __shfl_up(inc, d);
        if ((t & 63) >= d) inc += u;
    }
    if ((t & 63) == 63) wsum[t >> 6] = inc;
    __syncthreads();
    int wo = 0;
    for (int k = 0; k < (t >> 6); ++k) wo += wsum[k];
    int ex = wo + inc - loc;
    if (b0 + 0 < NBK) lofs[b0 + 0] = ex;
    if (b0 + 1 < NBK) lofs[b0 + 1] = ex + v0;
    if (b0 + 2 < NBK) lofs[b0 + 2] = ex + v0 + v1;
    if (b0 + 3 < NBK) lofs[b0 + 3] = ex + v0 + v1 + v2;
    __syncthreads();
    // reserve global ranges (one atomic per WG,bucket), reset counters
    for (int k = t; k < NBK; k += 256) {
        int c = c1[k];
        if (c) {
            int gb = atomicAdd(&tail[k], c);
            dlt[k] = gb - lofs[k];
        }
        c1[k] = 0;
    }
    __syncthreads();
    // pass 2: scatter into LDS chunk (sorted by bucket) + bucket-id sidecar
    for (int g = t; g < ng; g += 256) {
        int4 d = ((const int4*)dst)[g0 + g];
        int4 s = ((const int4*)src)[g0 + g];
        int bb, r, p;
        bb = d.x >> BSH; r = atomicAdd(&c1[bb], 1); p = lofs[bb] + r;
        chunk[p] = ((unsigned)(d.x & (BNODES - 1)) << 19) | (unsigned)s.x;
        bid[p] = (unsigned short)bb;
        bb = d.y >> BSH; r = atomicAdd(&c1[bb], 1); p = lofs[bb] + r;
        chunk[p] = ((unsigned)(d.y & (BNODES - 1)) << 19) | (unsigned)s.y;
        bid[p] = (unsigned short)bb;
        bb = d.z >> BSH; r = atomicAdd(&c1[bb], 1); p = lofs[bb] + r;
        chunk[p] = ((unsigned)(d.z & (BNODES - 1)) << 19) | (unsigned)s.z;
        bid[p] = (unsigned short)bb;
        bb = d.w >> BSH; r = atomicAdd(&c1[bb], 1); p = lofs[bb] + r;
        chunk[p] = ((unsigned)(d.w & (BNODES - 1)) << 19) | (unsigned)s.w;
        bid[p] = (unsigned short)bb;
    }
    __syncthreads();
    // burst write: consecutive threads -> consecutive run addresses
    for (int p = t; p < ne; p += 256) {
        int bb = bid[p];
        int idx = p + dlt[bb];
        if (idx < (bb + 1) * BCAP) bins[idx] = chunk[p];
    }
}

// -------- Stage 1 fallback (R6): direct scattered write --------
__global__ __launch_bounds__(256) void k_binA(const int* __restrict__ src,
                                              const int* __restrict__ dst,
                                              int* __restrict__ tail,
                                              unsigned* __restrict__ bins) {
    __shared__ int cnt[NBK];
    __shared__ int bbase[NBK];
    const int t = threadIdx.x;
    for (int k = t; k < NBK; k += 256) cnt[k] = 0;
    __syncthreads();
    const long e0 = (long)blockIdx.x * ECHUNK;
    const int ne = (int)min((long)ECHUNK, (long)NE - e0);
    const int g0 = (int)(e0 >> 2);
    const int ng = ne >> 2;
    for (int g = t; g < ng; g += 256) {
        int4 d = ((const int4*)dst)[g0 + g];
        atomicAdd(&cnt[d.x >> BSH], 1);
        atomicAdd(&cnt[d.y >> BSH], 1);
        atomicAdd(&cnt[d.z >> BSH], 1);
        atomicAdd(&cnt[d.w >> BSH], 1);
    }
    __syncthreads();
    for (int k = t; k < NBK; k += 256) {
        int c = cnt[k];
        bbase[k] = c ? atomicAdd(&tail[k], c) : 0;
        cnt[k] = 0;
    }
    __syncthreads();
    for (int g = t; g < ng; g += 256) {
        int4 d = ((const int4*)dst)[g0 + g];
        int4 s = ((const int4*)src)[g0 + g];
        int b, r, idx;
        b = d.x >> BSH; r = atomicAdd(&cnt[b], 1); idx = bbase[b] + r;
        if (idx < (b + 1) * BCAP)
            bins[idx] = ((unsigned)(d.x & (BNODES - 1)) << 19) | (unsigned)s.x;
        b = d.y >> BSH; r = atomicAdd(&cnt[b], 1); idx = bbase[b] + r;
        if (idx < (b + 1) * BCAP)
            bins[idx] = ((unsigned)(d.y & (BNODES - 1)) << 19) | (unsigned)s.y;
        b = d.z >> BSH; r = atomicAdd(&cnt[b], 1); idx = bbase[b] + r;
        if (idx < (b + 1) * BCAP)
            bins[idx] = ((unsigned)(d.z & (BNODES - 1)) << 19) | (unsigned)s.z;
        b = d.w >> BSH; r = atomicAdd(&cnt[b], 1); idx = bbase[b] + r;
        if (idx < (b + 1) * BCAP)
            bins[idx] = ((unsigned)(d.w & (BNODES - 1)) << 19) | (unsigned)s.w;
    }
}

// -------- Stage 2 (R7): LDS-staged CSR sort + coalesced write-out --------
__global__ __launch_bounds__(256) void k_rebinD(const unsigned* __restrict__ bins0,
                                                const int* __restrict__ tail,
                                                unsigned* __restrict__ bins1,
                                                int* __restrict__ astart,
                                                int* __restrict__ cnt) {
    extern __shared__ unsigned sb[];   // BCAP entries (72 KB)
    __shared__ int c1[BNODES];
    __shared__ int wb[BNODES];
    __shared__ int c2[BNODES];
    __shared__ int wsum[4];
    const int b = blockIdx.x;
    const int t = threadIdx.x;
    c1[t] = 0; c1[t + 256] = 0;
    c2[t] = 0; c2[t + 256] = 0;
    __syncthreads();
    const int base = b * BCAP;
    const int n = min(tail[b] - base, BCAP);
    const unsigned* e0 = bins0 + base;
    for (int j = t; j < n; j += 256) atomicAdd(&c1[e0[j] >> 19], 1);
    __syncthreads();
    // exclusive prefix of 4-aligned row sizes (512 values; thread t covers 2)
    int a0 = c1[2 * t], a1 = c1[2 * t + 1];
    int p0 = (a0 + 3) & ~3, p1 = (a1 + 3) & ~3;
    int loc = p0 + p1, inc = loc;
#pragma unroll
    for (int d = 1; d < 64; d <<= 1) {
        int u = __shfl_up(inc, d);
        if ((t & 63) >= d) inc += u;
    }
    if ((t & 63) == 63) wsum[t >> 6] = inc;
    __syncthreads();
    int wo = 0;
    for (int k = 0; k < (t >> 6); ++k) wo += wsum[k];
    int ex = wo + inc - loc;
    wb[2 * t] = ex;
    wb[2 * t + 1] = ex + p0;
    const int nb = b << BSH;
    cnt[nb + 2 * t] = a0;
    cnt[nb + 2 * t + 1] = a1;
    astart[nb + 2 * t] = base + ex;
    astart[nb + 2 * t + 1] = base + ex + p0;
    __syncthreads();
    // scatter into LDS staging (ranks via LDS atomics)
    for (int j = t; j < n; j += 256) {
        unsigned v = e0[j];
        int l = v >> 19;
        int r = atomicAdd(&c2[l], 1);
        int p = wb[l] + r;
        if (p < BCAP) sb[p] = v & 0x7FFFFu;
    }
    __syncthreads();
    // coalesced uint4 stream-out
    int span = wb[BNODES - 1] + ((c1[BNODES - 1] + 3) & ~3);
    if (span > BCAP) span = BCAP;
    const int nq = span >> 2;  // span % 4 == 0
    uint4* d4 = (uint4*)(bins1 + base);
    const uint4* s4 = (const uint4*)sb;
    for (int q = t; q < nq; q += 256) d4[q] = s4[q];
}

// -------- Stage 2 fallback (R6): in-window scattered sort --------
__global__ __launch_bounds__(256) void k_rebinC(const unsigned* __restrict__ bins0,
                                                const int* __restrict__ tail,
                                                unsigned* __restrict__ bins1,
                                                int* __restrict__ astart,
                                                int* __restrict__ cnt) {
    __shared__ int c1[BNODES];
    __shared__ int wb[BNODES];
    __shared__ int c2[BNODES];
    const int b = blockIdx.x;
    const int t = threadIdx.x;
    c1[t] = 0; c1[t + 256] = 0;
    c2[t] = 0; c2[t + 256] = 0;
    __syncthreads();
    const int base = b * BCAP;
    const int n = min(tail[b] - base, BCAP);
    const unsigned* e0 = bins0 + base;
    for (int j = t; j < n; j += 256) atomicAdd(&c1[e0[j] >> 19], 1);
    __syncthreads();
    if (t == 0) {
        int o = 0;
        for (int r = 0; r < BNODES; ++r) {
            wb[r] = o;
            o = (o + c1[r] + 3) & ~3;
        }
    }
    __syncthreads();
    const int nb = b << BSH;
    cnt[nb + t] = c1[t];
    cnt[nb + t + 256] = c1[t + 256];
    astart[nb + t] = base + wb[t];
    astart[nb + t + 256] = base + wb[t + 256];
    for (int j = t; j < n; j += 256) {
        unsigned v = e0[j];
        int l = v >> 19;
        int k = atomicAdd(&c2[l], 1);
        int idx = wb[l] + k;
        if (idx < BCAP) bins1[base + idx] = v & 0x7FFFFu;
    }
}

// T1: dinv = rsqrt(deg+1) (fused), hp = dinv * (x @ W1.T)
__global__ __launch_bounds__(256) void k_t1n(const float* __restrict__ x,
                                             const float* __restrict__ W,
                                             const int* __restrict__ cnt,
                                             float* __restrict__ dinv,
                                             float* __restrict__ hp) {
    int i = blockIdx.x * 256 + threadIdx.x;
    if (i >= NN) return;
    float4 x0 = ((const float4*)x)[2 * i];
    float4 x1 = ((const float4*)x)[2 * i + 1];
    float xi[8] = {x0.x, x0.y, x0.z, x0.w, x1.x, x1.y, x1.z, x1.w};
    float di = rsqrtf((float)cnt[i] + 1.0f);  // +1 self-loop
    dinv[i] = di;
    float o[4];
#pragma unroll
    for (int j = 0; j < 4; ++j) {
        float s = 0.f;
#pragma unroll
        for (int k = 0; k < 8; ++k) s = fmaf(xi[k], W[j * 8 + k], s);
        o[j] = di * s;
    }
    ((float4*)hp)[i] = make_float4(o[0], o[1], o[2], o[3]);
}

// Per-node CSR gather + fused finish (register accumulation, 8 loads in
// flight, no LDS, masked tail via index-select).
template <int IND, int OUTD, bool RELU>
__global__ __launch_bounds__(256) void g_csr(const int* __restrict__ astart,
                                             const int* __restrict__ cnt,
                                             const unsigned* __restrict__ bins,
                                             const float* __restrict__ dinv,
                                             const float* __restrict__ hin,
                                             const float* __restrict__ bp,
                                             const float* __restrict__ Wn,
                                             float* __restrict__ hout) {
    int i = blockIdx.x * 256 + threadIdx.x;
    if (i >= NN) return;
    const int cn = cnt[i];
    const uint4* rp = (const uint4*)bins + (astart[i] >> 2);
    float acc[IND];
    if constexpr (IND == 4) {
        float4 sv = ((const float4*)hin)[i];
        acc[0] = sv.x; acc[1] = sv.y; acc[2] = sv.z; acc[3] = sv.w;
    } else {
        float2 sv = ((const float2*)hin)[i];
        acc[0] = sv.x; acc[1] = sv.y;
    }
    const int full = cn >> 2, rem = cn & 3;
    int j = 0;
    for (; j + 2 <= full; j += 2) {
        uint4 a = rp[j], c = rp[j + 1];
        if constexpr (IND == 4) {
            float4 h0 = ((const float4*)hin)[a.x];
            float4 h1 = ((const float4*)hin)[a.y];
            float4 h2 = ((const float4*)hin)[a.z];
            float4 h3 = ((const float4*)hin)[a.w];
            float4 h4 = ((const float4*)hin)[c.x];
            float4 h5 = ((const float4*)hin)[c.y];
            float4 h6 = ((const float4*)hin)[c.z];
            float4 h7 = ((const float4*)hin)[c.w];
            acc[0] += ((h0.x + h1.x) + (h2.x + h3.x)) + ((h4.x + h5.x) + (h6.x + h7.x));
            acc[1] += ((h0.y + h1.y) + (h2.y + h3.y)) + ((h4.y + h5.y) + (h6.y + h7.y));
            acc[2] += ((h0.z + h1.z) + (h2.z + h3.z)) + ((h4.z + h5.z) + (h6.z + h7.z));
            acc[3] += ((h0.w + h1.w) + (h2.w + h3.w)) + ((h4.w + h5.w) + (h6.w + h7.w));
        } else {
            float2 h0 = ((const float2*)hin)[a.x];
            float2 h1 = ((const float2*)hin)[a.y];
            float2 h2 = ((const float2*)hin)[a.z];
            float2 h3 = ((const float2*)hin)[a.w];
            float2 h4 = ((const float2*)hin)[c.x];
            float2 h5 = ((const float2*)hin)[c.y];
            float2 h6 = ((const float2*)hin)[c.z];
            float2 h7 = ((const float2*)hin)[c.w];
            acc[0] += ((h0.x + h1.x) + (h2.x + h3.x)) + ((h4.x + h5.x) + (h6.x + h7.x));
            acc[1] += ((h0.y + h1.y) + (h2.y + h3.y)) + ((h4.y + h5.y) + (h6.y + h7.y));
        }
    }
    if (j < full) {
        uint4 a = rp[j];
        if constexpr (IND == 4) {
            float4 h0 = ((const float4*)hin)[a.x];
            float4 h1 = ((const float4*)hin)[a.y];
            float4 h2 = ((const float4*)hin)[a.z];
            float4 h3 = ((const float4*)hin)[a.w];
            acc[0] += (h0.x + h1.x) + (h2.x + h3.x);
            acc[1] += (h0.y + h1.y) + (h2.y + h3.y);
            acc[2] += (h0.z + h1.z) + (h2.z + h3.z);
            acc[3] += (h0.w + h1.w) + (h2.w + h3.w);
        } else {
            float2 h0 = ((const float2*)hin)[a.x];
            float2 h1 = ((const float2*)hin)[a.y];
            float2 h2 = ((const float2*)hin)[a.z];
            float2 h3 = ((const float2*)hin)[a.w];
            acc[0] += (h0.x + h1.x) + (h2.x + h3.x);
            acc[1] += (h0.y + h1.y) + (h2.y + h3.y);
        }
    }
    if (rem) {
        uint4 a = rp[full];
        unsigned s1 = rem > 1 ? a.y : a.x;
        unsigned s2 = rem > 2 ? a.z : a.x;
        float w1 = rem > 1 ? 1.f : 0.f;
        float w2 = rem > 2 ? 1.f : 0.f;
        if constexpr (IND == 4) {
            float4 h0 = ((const float4*)hin)[a.x];
            float4 h1 = ((const float4*)hin)[s1];
            float4 h2 = ((const float4*)hin)[s2];
            acc[0] += h0.x + w1 * h1.x + w2 * h2.x;
            acc[1] += h0.y + w1 * h1.y + w2 * h2.y;
            acc[2] += h0.z + w1 * h1.z + w2 * h2.z;
            acc[3] += h0.w + w1 * h1.w + w2 * h2.w;
        } else {
            float2 h0 = ((const float2*)hin)[a.x];
            float2 h1 = ((const float2*)hin)[s1];
            float2 h2 = ((const float2*)hin)[s2];
            acc[0] += h0.x + w1 * h1.x + w2 * h2.x;
            acc[1] += h0.y + w1 * h1.y + w2 * h2.y;
        }
    }
    const float di = dinv[i];
    float h[IND];
#pragma unroll
    for (int k = 0; k < IND; ++k) {
        float v = di * acc[k] + bp[k];
        h[k] = RELU ? fmaxf(v, 0.f) : tanhf(v);
    }
    float o[OUTD];
#pragma unroll
    for (int q = 0; q < OUTD; ++q) {
        float s = 0.f;
#pragma unroll
        for (int k = 0; k < IND; ++k) s = fmaf(h[k], Wn[q * IND + k], s);
        o[q] = di * s;
    }
    if constexpr (OUTD == 4)
        ((float4*)hout)[i] = make_float4(o[0], o[1], o[2], o[3]);
    else
        ((float2*)hout)[i] = make_float2(o[0], o[1]);
}

// Final gather: finish conv4 (tanh,b4) -> h[N,2] straight into out chunk.
__global__ __launch_bounds__(256) void g_csrF(const int* __restrict__ astart,
                                              const int* __restrict__ cnt,
                                              const unsigned* __restrict__ bins,
                                              const float* __restrict__ dinv,
                                              const float* __restrict__ hin,
                                              const float* __restrict__ b4,
                                              float* __restrict__ hout2) {
    int i = blockIdx.x * 256 + threadIdx.x;
    if (i >= NN) return;
    const int cn = cnt[i];
    const uint4* rp = (const uint4*)bins + (astart[i] >> 2);
    float2 sv = ((const float2*)hin)[i];
    float a0 = sv.x, a1 = sv.y;
    const int full = cn >> 2, rem = cn & 3;
    int j = 0;
    for (; j + 2 <= full; j += 2) {
        uint4 a = rp[j], c = rp[j + 1];
        float2 h0 = ((const float2*)hin)[a.x];
        float2 h1 = ((const float2*)hin)[a.y];
        float2 h2 = ((const float2*)hin)[a.z];
        float2 h3 = ((const float2*)hin)[a.w];
        float2 h4 = ((const float2*)hin)[c.x];
        float2 h5 = ((const float2*)hin)[c.y];
        float2 h6 = ((const float2*)hin)[c.z];
        float2 h7 = ((const float2*)hin)[c.w];
        a0 += ((h0.x + h1.x) + (h2.x + h3.x)) + ((h4.x + h5.x) + (h6.x + h7.x));
        a1 += ((h0.y + h1.y) + (h2.y + h3.y)) + ((h4.y + h5.y) + (h6.y + h7.y));
    }
    if (j < full) {
        uint4 a = rp[j];
        float2 h0 = ((const float2*)hin)[a.x];
        float2 h1 = ((const float2*)hin)[a.y];
        float2 h2 = ((const float2*)hin)[a.z];
        float2 h3 = ((const float2*)hin)[a.w];
        a0 += (h0.x + h1.x) + (h2.x + h3.x);
        a1 += (h0.y + h1.y) + (h2.y + h3.y);
    }
    if (rem) {
        uint4 a = rp[full];
        unsigned s1 = rem > 1 ? a.y : a.x;
        unsigned s2 = rem > 2 ? a.z : a.x;
        float w1 = rem > 1 ? 1.f : 0.f;
        float w2 = rem > 2 ? 1.f : 0.f;
        float2 h0 = ((const float2*)hin)[a.x];
        float2 h1 = ((const float2*)hin)[s1];
        float2 h2 = ((const float2*)hin)[s2];
        a0 += h0.x + w1 * h1.x + w2 * h2.x;
        a1 += h0.y + w1 * h1.y + w2 * h2.y;
    }
    const float di = dinv[i];
    float h0 = tanhf(di * a0 + b4[0]);
    float h1 = tanhf(di * a1 + b4[1]);
    ((float2*)hout2)[i] = make_float2(h0, h1);
}

// Head: out[n,k] = h[n]·Wc[k] + bc[k]. One float4 (4 consecutive k) per thread.
__global__ __launch_bounds__(256) void k_f2(const float* __restrict__ h,
                                            const float* __restrict__ Wc,
                                            const float* __restrict__ bc,
                                            float* __restrict__ out) {
    int t = blockIdx.x * 256 + threadIdx.x;  // NN*28 units
    if (t >= NN * 28) return;
    int n = t / 28;
    int r = t - n * 28;
    int k = 4 * r;
    float2 hv = ((const float2*)h)[n];
    float4 o;
    o.x = fmaf(hv.y, Wc[2 * k + 1], fmaf(hv.x, Wc[2 * k + 0], bc[k + 0]));
    o.y = fmaf(hv.y, Wc[2 * k + 3], fmaf(hv.x, Wc[2 * k + 2], bc[k + 1]));
    o.z = fmaf(hv.y, Wc[2 * k + 5], fmaf(hv.x, Wc[2 * k + 4], bc[k + 2]));
    o.w = fmaf(hv.y, Wc[2 * k + 7], fmaf(hv.x, Wc[2 * k + 6], bc[k + 3]));
    ((float4*)out)[(size_t)n * 28 + r] = o;
}

// ================= fallback: R1 atomic-scatter path =================

__global__ __launch_bounds__(256) void k_init_deg(float* __restrict__ deg) {
    int i = blockIdx.x * 256 + threadIdx.x;
    if (i < NN) deg[i] = 1.0f;
}

__global__ __launch_bounds__(256) void k_count(const int* __restrict__ dst,
                                               float* __restrict__ deg) {
    int t = blockIdx.x * 256 + threadIdx.x;
    int4 d = ((const int4*)dst)[t];
    aadd(deg + d.x, 1.0f); aadd(deg + d.y, 1.0f);
    aadd(deg + d.z, 1.0f); aadd(deg + d.w, 1.0f);
}

__global__ __launch_bounds__(256) void k_dinv(float* __restrict__ deg) {
    int i = blockIdx.x * 256 + threadIdx.x;
    if (i < NN) deg[i] = 1.0f / sqrtf(deg[i]);
}

__global__ __launch_bounds__(256) void k_t1(const float* __restrict__ x,
                                            const float* __restrict__ W,
                                            const float* __restrict__ dinv,
                                            float* __restrict__ hp,
                                            float* __restrict__ ac) {
    int i = blockIdx.x * 256 + threadIdx.x;
    if (i >= NN) return;
    float4 x0 = ((const float4*)x)[2 * i];
    float4 x1 = ((const float4*)x)[2 * i + 1];
    float xi[8] = {x0.x, x0.y, x0.z, x0.w, x1.x, x1.y, x1.z, x1.w};
    float di = dinv[i];
    float o[4];
#pragma unroll
    for (int j = 0; j < 4; ++j) {
        float s = 0.f;
#pragma unroll
        for (int k = 0; k < 8; ++k) s = fmaf(xi[k], W[j * 8 + k], s);
        o[j] = di * s;
    }
    ((float4*)hp)[i] = make_float4(o[0], o[1], o[2], o[3]);
    ((float4*)ac)[i] = make_float4(0.f, 0.f, 0.f, 0.f);
}

__global__ __launch_bounds__(256) void k_s4(const int* __restrict__ src,
                                            const int* __restrict__ dst,
                                            const float* __restrict__ hp,
                                            float* __restrict__ ac) {
    int t = blockIdx.x * 256 + threadIdx.x;
    int4 s = ((const int4*)src)[t];
    int4 d = ((const int4*)dst)[t];
    float4 h;
    h = ((const float4*)hp)[s.x];
    aadd(ac + 4 * d.x + 0, h.x); aadd(ac + 4 * d.x + 1, h.y);
    aadd(ac + 4 * d.x + 2, h.z); aadd(ac + 4 * d.x + 3, h.w);
    h = ((const float4*)hp)[s.y];
    aadd(ac + 4 * d.y + 0, h.x); aadd(ac + 4 * d.y + 1, h.y);
    aadd(ac + 4 * d.y + 2, h.z); aadd(ac + 4 * d.y + 3, h.w);
    h = ((const float4*)hp)[s.z];
    aadd(ac + 4 * d.z + 0, h.x); aadd(ac + 4 * d.z + 1, h.y);
    aadd(ac + 4 * d.z + 2, h.z); aadd(ac + 4 * d.z + 3, h.w);
    h = ((const float4*)hp)[s.w];
    aadd(ac + 4 * d.w + 0, h.x); aadd(ac + 4 * d.w + 1, h.y);
    aadd(ac + 4 * d.w + 2, h.z); aadd(ac + 4 * d.w + 3, h.w);
}

__global__ __launch_bounds__(256) void k_s2(const int* __restrict__ src,
                                            const int* __restrict__ dst,
                                            const float* __restrict__ hp,
                                            float* __restrict__ ac) {
    int t = blockIdx.x * 256 + threadIdx.x;
    int4 s = ((const int4*)src)[t];
    int4 d = ((const int4*)dst)[t];
    float2 h;
    h = ((const float2*)hp)[s.x];
    aadd(ac + 2 * d.x + 0, h.x); aadd(ac + 2 * d.x + 1, h.y);
    h = ((const float2*)hp)[s.y];
    aadd(ac + 2 * d.y + 0, h.x); aadd(ac + 2 * d.y + 1, h.y);
    h = ((const float2*)hp)[s.z];
    aadd(ac + 2 * d.z + 0, h.x); aadd(ac + 2 * d.z + 1, h.y);
    h = ((const float2*)hp)[s.w];
    aadd(ac + 2 * d.w + 0, h.x); aadd(ac + 2 * d.w + 1, h.y);
}

template <bool RELU>
__global__ __launch_bounds__(256) void k_t44(const float* __restrict__ dinv,
                                             float* __restrict__ hp,
                                             float* __restrict__ ac,
                                             const float* __restrict__ bprev,
                                             const float* __restrict__ Wn) {
    int i = blockIdx.x * 256 + threadIdx.x;
    if (i >= NN) return;
    float di = dinv[i];
    float4 hv = ((const float4*)hp)[i];
    float4 av = ((const float4*)ac)[i];
    float h[4];
    h[0] = di * (av.x + hv.x) + bprev[0];
    h[1] = di * (av.y + hv.y) + bprev[1];
    h[2] = di * (av.z + hv.z) + bprev[2];
    h[3] = di * (av.w + hv.w) + bprev[3];
#pragma unroll
    for (int k = 0; k < 4; ++k) h[k] = RELU ? fmaxf(h[k], 0.f) : tanhf(h[k]);
    float o[4];
#pragma unroll
    for (int j = 0; j < 4; ++j) {
        float s = 0.f;
#pragma unroll
        for (int k = 0; k < 4; ++k) s = fmaf(h[k], Wn[j * 4 + k], s);
        o[j] = di * s;
    }
    ((float4*)hp)[i] = make_float4(o[0], o[1], o[2], o[3]);
    ((float4*)ac)[i] = make_float4(0.f, 0.f, 0.f, 0.f);
}

__global__ __launch_bounds__(256) void k_t42(const float* __restrict__ dinv,
                                             const float* __restrict__ hp4,
                                             const float* __restrict__ ac4,
                                             const float* __restrict__ bprev,
                                             const float* __restrict__ Wn,
                                             float* __restrict__ hp2,
                                             float* __restrict__ ac2) {
    int i = blockIdx.x * 256 + threadIdx.x;
    if (i >= NN) return;
    float di = dinv[i];
    float4 hv = ((const float4*)hp4)[i];
    float4 av = ((const float4*)ac4)[i];
    float h[4];
    h[0] = tanhf(di * (av.x + hv.x) + bprev[0]);
    h[1] = tanhf(di * (av.y + hv.y) + bprev[1]);
    h[2] = tanhf(di * (av.z + hv.z) + bprev[2]);
    h[3] = tanhf(di * (av.w + hv.w) + bprev[3]);
    float o0 = 0.f, o1 = 0.f;
#pragma unroll
    for (int k = 0; k < 4; ++k) {
        o0 = fmaf(h[k], Wn[k], o0);
        o1 = fmaf(h[k], Wn[4 + k], o1);
    }
    ((float2*)hp2)[i] = make_float2(di * o0, di * o1);
    ((float2*)ac2)[i] = make_float2(0.f, 0.f);
}

__global__ __launch_bounds__(256) void k_t22(const float* __restrict__ dinv,
                                             float* __restrict__ hp,
                                             float* __restrict__ ac,
                                             const float* __restrict__ bprev,
                                             const float* __restrict__ Wn) {
    int i = blockIdx.x * 256 + threadIdx.x;
    if (i >= NN) return;
    float di = dinv[i];
    float2 hv = ((const float2*)hp)[i];
    float2 av = ((const float2*)ac)[i];
    float h0 = fmaxf(di * (av.x + hv.x) + bprev[0], 0.f);
    float h1 = fmaxf(di * (av.y + hv.y) + bprev[1], 0.f);
    float o0 = fmaf(h1, Wn[1], h0 * Wn[0]);
    float o1 = fmaf(h1, Wn[3], h0 * Wn[2]);
    ((float2*)hp)[i] = make_float2(di * o0, di * o1);
    ((float2*)ac)[i] = make_float2(di * 0.f, di * 0.f);
}

__global__ __launch_bounds__(256) void k_f1(const float* __restrict__ dinv,
                                            const float* __restrict__ hp,
                                            float* __restrict__ ac,
                                            const float* __restrict__ b4,
                                            float* __restrict__ hout) {
    int i = blockIdx.x * 256 + threadIdx.x;
    if (i >= NN) return;
    float di = dinv[i];
    float2 hv = ((const float2*)hp)[i];
    float2 av = ((const float2*)ac)[i];
    float h0 = tanhf(di * (av.x + hv.x) + b4[0]);
    float h1 = tanhf(di * (av.y + hv.y) + b4[1]);
    ((float2*)hout)[i] = make_float2(h0, h1);
    ((float2*)ac)[i] = make_float2(h0, h1);
}

// ============================ launch ============================

extern "C" void kernel_launch(void* const* d_in, const int* in_sizes, int n_in,
                              void* d_out, int out_size, void* d_ws, size_t ws_size,
                              hipStream_t stream) {
    const float* x   = (const float*)d_in[0];
    const int*   ei  = (const int*)d_in[1];
    const int*   src = ei;
    const int*   dst = ei + NE;
    const float* W1 = (const float*)d_in[2];
    const float* b1 = (const float*)d_in[3];
    const float* W2 = (const float*)d_in[4];
    const float* b2 = (const float*)d_in[5];
    const float* W3 = (const float*)d_in[6];
    const float* b3 = (const float*)d_in[7];
    const float* W4 = (const float*)d_in[8];
    const float* b4 = (const float*)d_in[9];
    const float* Wc = (const float*)d_in[10];
    const float* bc = (const float*)d_in[11];
    float* out = (float*)d_out;
    float* hN2 = out + (size_t)112 * NN;   // second output chunk: h [N,2]

    const int NB_N  = (NN + 255) / 256;
    const int NB_E4 = NE / 4 / 256;        // 15625 exactly
    const int NB_F2 = (NN * 28 + 255) / 256;

    // one-time: enable >64KB dynamic LDS for the burst kernels
    static int dyn_ok = -1;
    if (dyn_ok < 0) {
        hipError_t e1 = hipFuncSetAttribute(
            reinterpret_cast<const void*>(k_binB),
            hipFuncAttributeMaxDynamicSharedMemorySize, DYN_BINB);
        hipError_t e2 = hipFuncSetAttribute(
            reinterpret_cast<const void*>(k_rebinD),
            hipFuncAttributeMaxDynamicSharedMemorySize, DYN_REBIN);
        dyn_ok = (e1 == hipSuccess && e2 == hipSuccess) ? 1 : 0;
    }

    // workspace (u32 units): 13N h-buffers + tail(1024) + cnt + astart
    //   + bins0 + bins1
    const size_t binsz = (size_t)NBK * BCAP;            // 18,008,064
    const size_t nodesz = (size_t)NBK << BSH;           // 500,224
    const size_t need_new =
        ((size_t)13 * NN + 1024 + 2 * nodesz + 2 * binsz) * 4;  // ~174 MB

    if (ws_size >= need_new) {
        // ---- CSR-bucket register-gather path ----
        float* ws   = (float*)d_ws;
        float* dinv = ws;                                  // N
        float* hpA  = ws + (size_t)NN;                     // 4N
        float* hpB  = ws + (size_t)5 * NN;                 // 4N
        float* h2A  = ws + (size_t)9 * NN;                 // 2N
        float* h2B  = ws + (size_t)11 * NN;                // 2N
        int*   tail = (int*)(ws + (size_t)13 * NN);        // NBK (pad 1024)
        int*   cntA = tail + 1024;                         // node-indexed deg
        int*   astart = cntA + nodesz;                     // node-indexed row start
        unsigned* bins0 = (unsigned*)(astart + nodesz);    // NBK*BCAP
        unsigned* bins1 = bins0 + binsz;                   // NBK*BCAP (CSR)

        k_tinit<<<(NBK + 255) / 256, 256, 0, stream>>>(tail);
        if (dyn_ok) {
            k_binB<<<NBA, 256, DYN_BINB, stream>>>(src, dst, tail, bins0);
            k_rebinD<<<NBK, 256, DYN_REBIN, stream>>>(bins0, tail, bins1, astart, cntA);
        } else {
            k_binA<<<NBA, 256, 0, stream>>>(src, dst, tail, bins0);
            k_rebinC<<<NBK, 256, 0, stream>>>(bins0, tail, bins1, astart, cntA);
        }
        k_t1n<<<NB_N, 256, 0, stream>>>(x, W1, cntA, dinv, hpA);
        // conv1 finish (relu,b1) + W2 transform
        g_csr<4, 4, true ><<<NB_N, 256, 0, stream>>>(astart, cntA, bins1, dinv, hpA, b1, W2, hpB);
        // conv2 finish (tanh,b2) + W3 transform
        g_csr<4, 2, false><<<NB_N, 256, 0, stream>>>(astart, cntA, bins1, dinv, hpB, b2, W3, h2A);
        // conv3 finish (relu,b3) + W4 transform
        g_csr<2, 2, true ><<<NB_N, 256, 0, stream>>>(astart, cntA, bins1, dinv, h2A, b3, W4, h2B);
        // conv4 finish (tanh,b4) -> h, straight into out chunk
        g_csrF<<<NB_N, 256, 0, stream>>>(astart, cntA, bins1, dinv, h2B, b4, hN2);
        k_f2<<<NB_F2, 256, 0, stream>>>(hN2, Wc, bc, out);
    } else {
        // ---- fallback: R1 atomic-scatter path (passed @10.46 ms) ----
        float* ws   = (float*)d_ws;
        float* dinv = ws;
        float* hp4  = ws + (size_t)NN;
        float* ac4  = ws + (size_t)5 * NN;
        float* hp2  = ws + (size_t)9 * NN;
        float* ac2  = ws + (size_t)11 * NN;

        k_init_deg<<<NB_N, 256, 0, stream>>>(dinv);
        k_count<<<NB_E4, 256, 0, stream>>>(dst, dinv);
        k_dinv<<<NB_N, 256, 0, stream>>>(dinv);
        k_t1<<<NB_N, 256, 0, stream>>>(x, W1, dinv, hp4, ac4);
        k_s4<<<NB_E4, 256, 0, stream>>>(src, dst, hp4, ac4);
        k_t44<true><<<NB_N, 256, 0, stream>>>(dinv, hp4, ac4, b1, W2);
        k_s4<<<NB_E4, 256, 0, stream>>>(src, dst, hp4, ac4);
        k_t42<<<NB_N, 256, 0, stream>>>(dinv, hp4, ac4, b2, W3, hp2, ac2);
        k_s2<<<NB_E4, 256, 0, stream>>>(src, dst, hp2, ac2);
        k_t22<<<NB_N, 256, 0, stream>>>(dinv, hp2, ac2, b3, W4);
        k_s2<<<NB_E4, 256, 0, stream>>>(src, dst, hp2, ac2);
        k_f1<<<NB_N, 256, 0, stream>>>(dinv, hp2, ac2, b4, hN2);
        k_f2<<<NB_F2, 256, 0, stream>>>(ac2, Wc, bc, out);
    }
}